// Round 1
// baseline (285.958 us; speedup 1.0000x reference)
//
#include <hip/hip_runtime.h>
#include <hip/hip_bf16.h>

typedef __bf16 bf16;
typedef __bf16 bf16x8 __attribute__((ext_vector_type(8)));
typedef float f32x4 __attribute__((ext_vector_type(4)));

#define S_DIM 128
#define L_DIM 512
#define D_DIM 256
#define NQ    1024   // concatenated q|k|v|g columns

// ---------------- K0: pack weights to bf16, transposed to N-major ----------------
__global__ void pack_weights(const float* __restrict__ wq, const float* __restrict__ wk,
                             const float* __restrict__ wv, const float* __restrict__ wg,
                             const float* __restrict__ wo,
                             bf16* __restrict__ wcat_t, bf16* __restrict__ wo_t) {
  int idx = blockIdx.x * 256 + threadIdx.x;
  const int total1 = NQ * D_DIM; // WcatT [1024][256]
  if (idx < total1) {
    int j = idx >> 8;      // output column 0..1023
    int d = idx & 255;     // k index
    const float* w = (j < 256) ? wq : (j < 512) ? wk : (j < 768) ? wv : wg;
    wcat_t[idx] = (bf16)w[d * 256 + (j & 255)];
  } else {
    int i2 = idx - total1; // woT [256][256]: woT[d][hc] = wo[hc][d]
    if (i2 < D_DIM * D_DIM) {
      int dcol = i2 >> 8, k = i2 & 255;
      wo_t[i2] = (bf16)wo[k * 256 + dcol];
    }
  }
}

// ---------------- K1: LayerNorm, one wave per row, write bf16 ----------------
__global__ __launch_bounds__(256) void ln_kernel(const float* __restrict__ x,
                                                 const float* __restrict__ sc,
                                                 const float* __restrict__ bs,
                                                 bf16* __restrict__ y) {
  int wid  = threadIdx.x >> 6;
  int lane = threadIdx.x & 63;
  int row  = blockIdx.x * 4 + wid;
  float4 v = ((const float4*)(x + (size_t)row * D_DIM))[lane];
  float s = v.x + v.y + v.z + v.w;
  #pragma unroll
  for (int m = 32; m; m >>= 1) s += __shfl_xor(s, m);
  float mu = s * (1.0f / 256.0f);
  float dx = v.x - mu, dy = v.y - mu, dz = v.z - mu, dw = v.w - mu;
  float s2 = dx * dx + dy * dy + dz * dz + dw * dw;
  #pragma unroll
  for (int m = 32; m; m >>= 1) s2 += __shfl_xor(s2, m);
  float rs = rsqrtf(s2 * (1.0f / 256.0f) + 1e-5f);
  float4 scv = ((const float4*)sc)[lane];
  float4 bsv = ((const float4*)bs)[lane];
  union { uint2 u; bf16 b[4]; } o;
  o.b[0] = (bf16)(dx * rs * scv.x + bsv.x);
  o.b[1] = (bf16)(dy * rs * scv.y + bsv.y);
  o.b[2] = (bf16)(dz * rs * scv.z + bsv.z);
  o.b[3] = (bf16)(dw * rs * scv.w + bsv.w);
  ((uint2*)y)[(size_t)row * 64 + lane] = o.u;
}

// ---------------- GEMM: A[M][256] bf16 @ Bt[N][256] bf16 ----------------
// MODE 0: C = qkvg bf16 [M][1024], sigmoid(+bg) on cols >= 768
// MODE 1: C = out  f32  [M][256], + bo
__device__ __forceinline__ bf16x8 ld_swz(const bf16* base, int row, int kk) {
  // row stride 512B, 16B-slot XOR swizzle by row&7 -> conflict-free b128
  return *(const bf16x8*)((const char*)base + row * 512 + (((kk * 2) ^ ((row & 7) << 4))));
}

template <int MODE>
__global__ __launch_bounds__(256) void gemm_bt(const bf16* __restrict__ A,
                                               const bf16* __restrict__ Bt,
                                               void* __restrict__ Cout,
                                               const float* __restrict__ bias,
                                               int N) {
  __shared__ __align__(16) bf16 As[64 * 256];
  __shared__ __align__(16) bf16 Bs[64 * 256];
  int tid = threadIdx.x;
  int m0 = blockIdx.x * 64;
  int n0 = blockIdx.y * 64;
  for (int idx = tid; idx < 64 * 32; idx += 256) {
    int r = idx >> 5, c = idx & 31;           // c: 16B chunk (8 bf16)
    int sw = (c * 16) ^ ((r & 7) << 4);
    *(uint4*)((char*)As + r * 512 + sw) = *(const uint4*)(A  + (size_t)(m0 + r) * 256 + c * 8);
    *(uint4*)((char*)Bs + r * 512 + sw) = *(const uint4*)(Bt + (size_t)(n0 + r) * 256 + c * 8);
  }
  __syncthreads();
  int wid = tid >> 6, lane = tid & 63;
  int wr = wid >> 1, wc = wid & 1;
  int lrow = lane & 15, lk = (lane >> 4) * 8;
  f32x4 acc[2][2] = {};
  #pragma unroll
  for (int k0 = 0; k0 < 256; k0 += 32) {
    bf16x8 a[2], b[2];
    #pragma unroll
    for (int t = 0; t < 2; t++) {
      a[t] = ld_swz(As, wr * 32 + t * 16 + lrow, k0 + lk);
      b[t] = ld_swz(Bs, wc * 32 + t * 16 + lrow, k0 + lk);
    }
    #pragma unroll
    for (int i = 0; i < 2; i++)
      #pragma unroll
      for (int j = 0; j < 2; j++)
        acc[i][j] = __builtin_amdgcn_mfma_f32_16x16x32_bf16(a[i], b[j], acc[i][j], 0, 0, 0);
  }
  int rbase = (lane >> 4) * 4;
  #pragma unroll
  for (int i = 0; i < 2; i++)
    #pragma unroll
    for (int j = 0; j < 2; j++)
      #pragma unroll
      for (int r = 0; r < 4; r++) {
        int grow = m0 + wr * 32 + i * 16 + rbase + r;
        int gcol = n0 + wc * 32 + j * 16 + lrow;
        float val = acc[i][j][r];
        if (MODE == 0) {
          if (gcol >= 768) {
            val += bias[gcol - 768];
            val = 1.0f / (1.0f + __expf(-val));
          }
          ((bf16*)Cout)[(size_t)grow * N + gcol] = (bf16)val;
        } else {
          val += bias[gcol];
          ((float*)Cout)[(size_t)grow * N + gcol] = val;
        }
      }
}

// ---------------- K3: attention per (residue, head) ----------------
// qkvg row = s*L + res, cols: q[0:256) k[256:512) v[512:768) g[768:1024), col=h*32+c
__global__ __launch_bounds__(256) void attn_kernel(const bf16* __restrict__ qkvg,
                                                   bf16* __restrict__ obuf) {
  __shared__ __align__(16) bf16 q_lds[128 * 40];
  __shared__ __align__(16) bf16 k_lds[128 * 40];
  __shared__ __align__(16) bf16 vt_lds[32 * 136];
  __shared__ __align__(16) bf16 p_lds[128 * 136];
  int bid = blockIdx.x;
  int res = bid >> 3;
  int h   = bid & 7;
  int tid = threadIdx.x;
  size_t base = (size_t)res * NQ + h * 32;

  // stage Q, K (row-major, padded) and V transposed
  for (int idx = tid; idx < 128 * 4; idx += 256) {
    int s = idx >> 2, c = (idx & 3) * 8;
    size_t g = (size_t)s * L_DIM * NQ + base + c;
    *(uint4*)(&q_lds[s * 40 + c]) = *(const uint4*)(qkvg + g);
    *(uint4*)(&k_lds[s * 40 + c]) = *(const uint4*)(qkvg + g + 256);
  }
  for (int idx = tid; idx < 128 * 4; idx += 256) {
    int t = idx >> 2, c = (idx & 3) * 8;
    union { uint4 u; bf16 e[8]; } v;
    v.u = *(const uint4*)(qkvg + (size_t)t * L_DIM * NQ + base + 512 + c);
    #pragma unroll
    for (int j = 0; j < 8; j++) vt_lds[(c + j) * 136 + t] = v.e[j];
  }
  __syncthreads();

  int wid = tid >> 6, lane = tid & 63;
  int lrow = lane & 15, lk = (lane >> 4) * 8;
  int s0 = wid * 32;

  // QK^T: per wave 32 rows x 128 cols
  f32x4 sc[2][8] = {};
  bf16x8 a0 = *(const bf16x8*)(&q_lds[(s0 + lrow) * 40 + lk]);
  bf16x8 a1 = *(const bf16x8*)(&q_lds[(s0 + 16 + lrow) * 40 + lk]);
  #pragma unroll
  for (int tc = 0; tc < 8; tc++) {
    bf16x8 b = *(const bf16x8*)(&k_lds[(tc * 16 + lrow) * 40 + lk]);
    sc[0][tc] = __builtin_amdgcn_mfma_f32_16x16x32_bf16(a0, b, sc[0][tc], 0, 0, 0);
    sc[1][tc] = __builtin_amdgcn_mfma_f32_16x16x32_bf16(a1, b, sc[1][tc], 0, 0, 0);
  }
  const float scale = 0.17677669529663687f; // 1/sqrt(32)
  #pragma unroll
  for (int i = 0; i < 2; i++)
    #pragma unroll
    for (int tc = 0; tc < 8; tc++) sc[i][tc] *= scale;

  // softmax over t (cols): row s lives in one 16-lane group at reg r
  #pragma unroll
  for (int tr = 0; tr < 2; tr++)
    #pragma unroll
    for (int r = 0; r < 4; r++) {
      float m = -1e30f;
      #pragma unroll
      for (int tc = 0; tc < 8; tc++) m = fmaxf(m, sc[tr][tc][r]);
      #pragma unroll
      for (int msk = 8; msk; msk >>= 1) m = fmaxf(m, __shfl_xor(m, msk));
      float ssum = 0.f;
      #pragma unroll
      for (int tc = 0; tc < 8; tc++) {
        float p = __expf(sc[tr][tc][r] - m);
        sc[tr][tc][r] = p;
        ssum += p;
      }
      #pragma unroll
      for (int msk = 8; msk; msk >>= 1) ssum += __shfl_xor(ssum, msk);
      float inv = 1.0f / ssum;
      int prow = s0 + tr * 16 + (lane >> 4) * 4 + r;
      #pragma unroll
      for (int tc = 0; tc < 8; tc++)
        p_lds[prow * 136 + tc * 16 + lrow] = (bf16)(sc[tr][tc][r] * inv);
    }
  __syncthreads();

  // PV: per wave 32 rows x 32 cols, K=128
  f32x4 oc[2][2] = {};
  #pragma unroll
  for (int kc = 0; kc < 4; kc++) {
    bf16x8 pa0 = *(const bf16x8*)(&p_lds[(s0 + lrow) * 136 + kc * 32 + lk]);
    bf16x8 pa1 = *(const bf16x8*)(&p_lds[(s0 + 16 + lrow) * 136 + kc * 32 + lk]);
    bf16x8 b0  = *(const bf16x8*)(&vt_lds[lrow * 136 + kc * 32 + lk]);
    bf16x8 b1  = *(const bf16x8*)(&vt_lds[(16 + lrow) * 136 + kc * 32 + lk]);
    oc[0][0] = __builtin_amdgcn_mfma_f32_16x16x32_bf16(pa0, b0, oc[0][0], 0, 0, 0);
    oc[0][1] = __builtin_amdgcn_mfma_f32_16x16x32_bf16(pa0, b1, oc[0][1], 0, 0, 0);
    oc[1][0] = __builtin_amdgcn_mfma_f32_16x16x32_bf16(pa1, b0, oc[1][0], 0, 0, 0);
    oc[1][1] = __builtin_amdgcn_mfma_f32_16x16x32_bf16(pa1, b1, oc[1][1], 0, 0, 0);
  }

  // gate + store o bf16 [65536][256]
  int rbase = (lane >> 4) * 4;
  #pragma unroll
  for (int i = 0; i < 2; i++)
    #pragma unroll
    for (int j = 0; j < 2; j++)
      #pragma unroll
      for (int r = 0; r < 4; r++) {
        int srow = s0 + i * 16 + rbase + r;
        int c = j * 16 + lrow;
        float gv = (float)qkvg[(size_t)srow * L_DIM * NQ + base + 768 + c];
        float val = oc[i][j][r] * gv;
        obuf[((size_t)srow * L_DIM + res) * 256 + h * 32 + c] = (bf16)val;
      }
}

// ---------------- launch ----------------
extern "C" void kernel_launch(void* const* d_in, const int* in_sizes, int n_in,
                              void* d_out, int out_size, void* d_ws, size_t ws_size,
                              hipStream_t stream) {
  const float* msa      = (const float*)d_in[0];
  const float* ln_scale = (const float*)d_in[1];
  const float* ln_bias  = (const float*)d_in[2];
  const float* wq       = (const float*)d_in[3];
  const float* wk       = (const float*)d_in[4];
  const float* wv       = (const float*)d_in[5];
  const float* wg       = (const float*)d_in[6];
  const float* bg       = (const float*)d_in[7];
  const float* wo       = (const float*)d_in[8];
  const float* bo       = (const float*)d_in[9];
  float* out = (float*)d_out;

  char* ws = (char*)d_ws;
  bf16* wcat_t = (bf16*)ws;                                  // 512 KB
  bf16* wo_t   = (bf16*)(ws + 524288);                       // 128 KB
  bf16* qkvg   = (bf16*)(ws + 655360);                       // 128 MB
  bf16* obuf   = (bf16*)(ws + 655360 + 134217728ULL);        // 32 MB
  bf16* x_ln   = (bf16*)d_out;                               // 32 MB scratch inside out (dead before final GEMM)

  pack_weights<<<dim3(1280), dim3(256), 0, stream>>>(wq, wk, wv, wg, wo, wcat_t, wo_t);
  ln_kernel<<<dim3(65536 / 4), dim3(256), 0, stream>>>(msa, ln_scale, ln_bias, x_ln);
  gemm_bt<0><<<dim3(1024, 16), dim3(256), 0, stream>>>(x_ln, wcat_t, (void*)qkvg, bg, 1024);
  attn_kernel<<<dim3(4096), dim3(256), 0, stream>>>(qkvg, obuf);
  gemm_bt<1><<<dim3(1024, 4), dim3(256), 0, stream>>>(obuf, wo_t, (void*)out, bo, 256);
}

// Round 2
// 226.005 us; speedup vs baseline: 1.2653x; 1.2653x over previous
//
#include <hip/hip_runtime.h>
#include <hip/hip_bf16.h>

typedef __bf16 bf16;
typedef __bf16 bf16x8 __attribute__((ext_vector_type(8)));
typedef float f32x4 __attribute__((ext_vector_type(4)));

#define S_DIM 128
#define L_DIM 512
#define D_DIM 256
#define NQ    1024   // concatenated q|k|v|g columns

// async global->LDS, 16B per lane; lds must be the wave-uniform base
__device__ __forceinline__ void gl16(void* lds, const void* g) {
  __builtin_amdgcn_global_load_lds((const __attribute__((address_space(1))) void*)g,
                                   (__attribute__((address_space(3))) void*)lds,
                                   16, 0, 0);
}

// ---------------- K0: pack weights to bf16, transposed to N-major ----------------
__global__ void pack_weights(const float* __restrict__ wq, const float* __restrict__ wk,
                             const float* __restrict__ wv, const float* __restrict__ wg,
                             const float* __restrict__ wo,
                             bf16* __restrict__ wcat_t, bf16* __restrict__ wo_t) {
  int idx = blockIdx.x * 256 + threadIdx.x;
  const int total1 = NQ * D_DIM; // WcatT [1024][256]
  if (idx < total1) {
    int j = idx >> 8;      // output column 0..1023
    int d = idx & 255;     // k index
    const float* w = (j < 256) ? wq : (j < 512) ? wk : (j < 768) ? wv : wg;
    wcat_t[idx] = (bf16)w[d * 256 + (j & 255)];
  } else {
    int i2 = idx - total1; // woT [256][256]: woT[d][hc] = wo[hc][d]
    if (i2 < D_DIM * D_DIM) {
      int dcol = i2 >> 8, k = i2 & 255;
      wo_t[i2] = (bf16)wo[k * 256 + dcol];
    }
  }
}

// ---------------- K1: LayerNorm, one wave per row, write bf16 ----------------
__global__ __launch_bounds__(256) void ln_kernel(const float* __restrict__ x,
                                                 const float* __restrict__ sc,
                                                 const float* __restrict__ bs,
                                                 bf16* __restrict__ y) {
  int wid  = threadIdx.x >> 6;
  int lane = threadIdx.x & 63;
  int row  = blockIdx.x * 4 + wid;
  float4 v = ((const float4*)(x + (size_t)row * D_DIM))[lane];
  float s = v.x + v.y + v.z + v.w;
  #pragma unroll
  for (int m = 32; m; m >>= 1) s += __shfl_xor(s, m);
  float mu = s * (1.0f / 256.0f);
  float dx = v.x - mu, dy = v.y - mu, dz = v.z - mu, dw = v.w - mu;
  float s2 = dx * dx + dy * dy + dz * dz + dw * dw;
  #pragma unroll
  for (int m = 32; m; m >>= 1) s2 += __shfl_xor(s2, m);
  float rs = rsqrtf(s2 * (1.0f / 256.0f) + 1e-5f);
  float4 scv = ((const float4*)sc)[lane];
  float4 bsv = ((const float4*)bs)[lane];
  union { uint2 u; bf16 b[4]; } o;
  o.b[0] = (bf16)(dx * rs * scv.x + bsv.x);
  o.b[1] = (bf16)(dy * rs * scv.y + bsv.y);
  o.b[2] = (bf16)(dz * rs * scv.z + bsv.z);
  o.b[3] = (bf16)(dw * rs * scv.w + bsv.w);
  ((uint2*)y)[(size_t)row * 64 + lane] = o.u;
}

// ---------------- GEMM: A[M][256] bf16 @ Bt[N][256] bf16, m97 structure ----------------
// 128x128 tile, BK=64, single LDS buffer, 2 barriers/K-step, global_load_lds(16B).
// MODE 0: C = qkvg bf16 [M][1024], sigmoid(+bg) on cols >= 768
// MODE 1: C = out  f32  [M][256], + bo
template <int MODE, int NCOLS>
__global__ __launch_bounds__(256) void gemm128(const bf16* __restrict__ A,
                                               const bf16* __restrict__ Bt,
                                               void* __restrict__ Cout,
                                               const float* __restrict__ bias) {
  __shared__ __align__(16) bf16 As[128 * 64];
  __shared__ __align__(16) bf16 Bs[128 * 64];
  const int tid  = threadIdx.x;
  const int wid  = tid >> 6;
  const int lane = tid & 63;
  const int m0 = blockIdx.y * 128;
  const int n0 = blockIdx.x * 128;
  const int lrow = lane & 15;
  const int lk   = (lane >> 4) * 8;
  const int wr = wid >> 1, wc = wid & 1;

  const int ln8 = lane >> 3;        // 0..7 (row within 8-row chunk)
  const int c8  = (lane & 7) * 8;   // col element within 64-col tile

  const bf16* Arow = A  + (size_t)m0 * 256 + c8;
  const bf16* Brow = Bt + (size_t)n0 * 256 + c8;

  f32x4 acc[4][4] = {};

  #pragma unroll
  for (int ks = 0; ks < 4; ++ks) {
    const int k0 = ks * 64;
    // stage A,B tiles: wave wid stages chunks wid*4..wid*4+3 (1 KB each)
    #pragma unroll
    for (int t = 0; t < 4; ++t) {
      int chunk = wid * 4 + t;
      int r = chunk * 8 + ln8;
      gl16(&As[chunk * 512], Arow + (size_t)r * 256 + k0);
      gl16(&Bs[chunk * 512], Brow + (size_t)r * 256 + k0);
    }
    __syncthreads();   // drains vmcnt before barrier (compiler-emitted)
    #pragma unroll
    for (int kk = 0; kk < 64; kk += 32) {
      bf16x8 av[4], bv[4];
      #pragma unroll
      for (int i = 0; i < 4; ++i)
        av[i] = *(const bf16x8*)(As + (wr * 64 + i * 16 + lrow) * 64 + kk + lk);
      #pragma unroll
      for (int j = 0; j < 4; ++j)
        bv[j] = *(const bf16x8*)(Bs + (wc * 64 + j * 16 + lrow) * 64 + kk + lk);
      #pragma unroll
      for (int i = 0; i < 4; ++i)
        #pragma unroll
        for (int j = 0; j < 4; ++j)
          acc[i][j] = __builtin_amdgcn_mfma_f32_16x16x32_bf16(av[i], bv[j], acc[i][j], 0, 0, 0);
    }
    if (ks < 3) __syncthreads();   // all reads done before next stage overwrites
  }

  const bool isg = (MODE == 0) && (n0 >= 768);
  const int rb = (lane >> 4) * 4;
  #pragma unroll
  for (int i = 0; i < 4; ++i) {
    #pragma unroll
    for (int j = 0; j < 4; ++j) {
      int gcol = n0 + wc * 64 + j * 16 + lrow;
      #pragma unroll
      for (int r = 0; r < 4; ++r) {
        int grow = m0 + wr * 64 + i * 16 + rb + r;
        float v = acc[i][j][r];
        if (MODE == 0) {
          if (isg) {
            v += bias[gcol - 768];
            v = 1.0f / (1.0f + __expf(-v));
          }
          ((bf16*)Cout)[(size_t)grow * NCOLS + gcol] = (bf16)v;
        } else {
          ((float*)Cout)[(size_t)grow * NCOLS + gcol] = v + bias[gcol];
        }
      }
    }
  }
}

// ---------------- K3: attention per (residue, head) ----------------
// qkvg row = s*L + res, cols: q[0:256) k[256:512) v[512:768) g[768:1024), col=h*32+c
__global__ __launch_bounds__(256) void attn_kernel(const bf16* __restrict__ qkvg,
                                                   bf16* __restrict__ obuf) {
  __shared__ __align__(16) bf16 q_lds[128 * 40];
  __shared__ __align__(16) bf16 k_lds[128 * 40];
  __shared__ __align__(16) bf16 vt_lds[32 * 136];
  __shared__ __align__(16) bf16 p_lds[128 * 136];
  int bid = blockIdx.x;
  int res = bid >> 3;
  int h   = bid & 7;
  int tid = threadIdx.x;
  size_t base = (size_t)res * NQ + h * 32;

  // stage Q, K (row-major, padded) and V transposed
  for (int idx = tid; idx < 128 * 4; idx += 256) {
    int s = idx >> 2, c = (idx & 3) * 8;
    size_t g = (size_t)s * L_DIM * NQ + base + c;
    *(uint4*)(&q_lds[s * 40 + c]) = *(const uint4*)(qkvg + g);
    *(uint4*)(&k_lds[s * 40 + c]) = *(const uint4*)(qkvg + g + 256);
  }
  for (int idx = tid; idx < 128 * 4; idx += 256) {
    int t = idx >> 2, c = (idx & 3) * 8;
    union { uint4 u; bf16 e[8]; } v;
    v.u = *(const uint4*)(qkvg + (size_t)t * L_DIM * NQ + base + 512 + c);
    #pragma unroll
    for (int j = 0; j < 8; j++) vt_lds[(c + j) * 136 + t] = v.e[j];
  }
  __syncthreads();

  int wid = tid >> 6, lane = tid & 63;
  int lrow = lane & 15, lk = (lane >> 4) * 8;
  int s0 = wid * 32;

  // QK^T: per wave 32 rows x 128 cols
  f32x4 sc[2][8] = {};
  bf16x8 a0 = *(const bf16x8*)(&q_lds[(s0 + lrow) * 40 + lk]);
  bf16x8 a1 = *(const bf16x8*)(&q_lds[(s0 + 16 + lrow) * 40 + lk]);
  #pragma unroll
  for (int tc = 0; tc < 8; tc++) {
    bf16x8 b = *(const bf16x8*)(&k_lds[(tc * 16 + lrow) * 40 + lk]);
    sc[0][tc] = __builtin_amdgcn_mfma_f32_16x16x32_bf16(a0, b, sc[0][tc], 0, 0, 0);
    sc[1][tc] = __builtin_amdgcn_mfma_f32_16x16x32_bf16(a1, b, sc[1][tc], 0, 0, 0);
  }
  const float scale = 0.17677669529663687f; // 1/sqrt(32)
  #pragma unroll
  for (int i = 0; i < 2; i++)
    #pragma unroll
    for (int tc = 0; tc < 8; tc++) sc[i][tc] *= scale;

  // softmax over t (cols): row s lives in one 16-lane group at reg r
  #pragma unroll
  for (int tr = 0; tr < 2; tr++)
    #pragma unroll
    for (int r = 0; r < 4; r++) {
      float m = -1e30f;
      #pragma unroll
      for (int tc = 0; tc < 8; tc++) m = fmaxf(m, sc[tr][tc][r]);
      #pragma unroll
      for (int msk = 8; msk; msk >>= 1) m = fmaxf(m, __shfl_xor(m, msk));
      float ssum = 0.f;
      #pragma unroll
      for (int tc = 0; tc < 8; tc++) {
        float p = __expf(sc[tr][tc][r] - m);
        sc[tr][tc][r] = p;
        ssum += p;
      }
      #pragma unroll
      for (int msk = 8; msk; msk >>= 1) ssum += __shfl_xor(ssum, msk);
      float inv = 1.0f / ssum;
      int prow = s0 + tr * 16 + (lane >> 4) * 4 + r;
      #pragma unroll
      for (int tc = 0; tc < 8; tc++)
        p_lds[prow * 136 + tc * 16 + lrow] = (bf16)(sc[tr][tc][r] * inv);
    }
  __syncthreads();

  // PV: per wave 32 rows x 32 cols, K=128
  f32x4 oc[2][2] = {};
  #pragma unroll
  for (int kc = 0; kc < 4; kc++) {
    bf16x8 pa0 = *(const bf16x8*)(&p_lds[(s0 + lrow) * 136 + kc * 32 + lk]);
    bf16x8 pa1 = *(const bf16x8*)(&p_lds[(s0 + 16 + lrow) * 136 + kc * 32 + lk]);
    bf16x8 b0  = *(const bf16x8*)(&vt_lds[lrow * 136 + kc * 32 + lk]);
    bf16x8 b1  = *(const bf16x8*)(&vt_lds[(16 + lrow) * 136 + kc * 32 + lk]);
    oc[0][0] = __builtin_amdgcn_mfma_f32_16x16x32_bf16(pa0, b0, oc[0][0], 0, 0, 0);
    oc[0][1] = __builtin_amdgcn_mfma_f32_16x16x32_bf16(pa0, b1, oc[0][1], 0, 0, 0);
    oc[1][0] = __builtin_amdgcn_mfma_f32_16x16x32_bf16(pa1, b0, oc[1][0], 0, 0, 0);
    oc[1][1] = __builtin_amdgcn_mfma_f32_16x16x32_bf16(pa1, b1, oc[1][1], 0, 0, 0);
  }

  // gate + store o bf16 [65536][256]
  int rbase = (lane >> 4) * 4;
  #pragma unroll
  for (int i = 0; i < 2; i++)
    #pragma unroll
    for (int j = 0; j < 2; j++)
      #pragma unroll
      for (int r = 0; r < 4; r++) {
        int srow = s0 + i * 16 + rbase + r;
        int c = j * 16 + lrow;
        float gv = (float)qkvg[(size_t)srow * L_DIM * NQ + base + 768 + c];
        float val = oc[i][j][r] * gv;
        obuf[((size_t)srow * L_DIM + res) * 256 + h * 32 + c] = (bf16)val;
      }
}

// ---------------- launch ----------------
extern "C" void kernel_launch(void* const* d_in, const int* in_sizes, int n_in,
                              void* d_out, int out_size, void* d_ws, size_t ws_size,
                              hipStream_t stream) {
  const float* msa      = (const float*)d_in[0];
  const float* ln_scale = (const float*)d_in[1];
  const float* ln_bias  = (const float*)d_in[2];
  const float* wq       = (const float*)d_in[3];
  const float* wk       = (const float*)d_in[4];
  const float* wv       = (const float*)d_in[5];
  const float* wg       = (const float*)d_in[6];
  const float* bg       = (const float*)d_in[7];
  const float* wo       = (const float*)d_in[8];
  const float* bo       = (const float*)d_in[9];
  float* out = (float*)d_out;

  char* ws = (char*)d_ws;
  bf16* wcat_t = (bf16*)ws;                                  // 512 KB
  bf16* wo_t   = (bf16*)(ws + 524288);                       // 128 KB
  bf16* qkvg   = (bf16*)(ws + 655360);                       // 128 MB
  bf16* obuf   = (bf16*)(ws + 655360 + 134217728ULL);        // 32 MB
  bf16* x_ln   = (bf16*)d_out;                               // 32 MB scratch inside out (dead before final GEMM)

  pack_weights<<<dim3(1280), dim3(256), 0, stream>>>(wq, wk, wv, wg, wo, wcat_t, wo_t);
  ln_kernel<<<dim3(65536 / 4), dim3(256), 0, stream>>>(msa, ln_scale, ln_bias, x_ln);
  gemm128<0, 1024><<<dim3(8, 512), dim3(256), 0, stream>>>(x_ln, wcat_t, (void*)qkvg, bg);
  attn_kernel<<<dim3(4096), dim3(256), 0, stream>>>(qkvg, obuf);
  gemm128<1, 256><<<dim3(2, 512), dim3(256), 0, stream>>>(obuf, wo_t, (void*)out, bo);
}

// Round 3
// 166.104 us; speedup vs baseline: 1.7216x; 1.3606x over previous
//
#include <hip/hip_runtime.h>
#include <hip/hip_bf16.h>

typedef __bf16 bf16;
typedef __bf16 bf16x8 __attribute__((ext_vector_type(8)));
typedef float f32x4 __attribute__((ext_vector_type(4)));

#define S_DIM 128
#define L_DIM 512
#define D_DIM 256
#define NQ    1024   // concatenated q|k|v|g columns

// async global->LDS, 16B per lane; lds must be the wave-uniform base
__device__ __forceinline__ void gl16(void* lds, const void* g) {
  __builtin_amdgcn_global_load_lds((const __attribute__((address_space(1))) void*)g,
                                   (__attribute__((address_space(3))) void*)lds,
                                   16, 0, 0);
}

// ---------------- K0: pack weights to bf16, transposed to N-major ----------------
__global__ void pack_weights(const float* __restrict__ wq, const float* __restrict__ wk,
                             const float* __restrict__ wv, const float* __restrict__ wg,
                             const float* __restrict__ wo,
                             bf16* __restrict__ wcat_t, bf16* __restrict__ wo_t) {
  int idx = blockIdx.x * 256 + threadIdx.x;
  const int total1 = NQ * D_DIM; // WcatT [1024][256]
  if (idx < total1) {
    int j = idx >> 8;      // output column 0..1023
    int d = idx & 255;     // k index
    const float* w = (j < 256) ? wq : (j < 512) ? wk : (j < 768) ? wv : wg;
    wcat_t[idx] = (bf16)w[d * 256 + (j & 255)];
  } else {
    int i2 = idx - total1; // woT [256][256]: woT[d][hc] = wo[hc][d]
    if (i2 < D_DIM * D_DIM) {
      int dcol = i2 >> 8, k = i2 & 255;
      wo_t[i2] = (bf16)wo[k * 256 + dcol];
    }
  }
}

// ---------------- K1: LayerNorm, one wave per row, write bf16 ----------------
__global__ __launch_bounds__(256) void ln_kernel(const float* __restrict__ x,
                                                 const float* __restrict__ sc,
                                                 const float* __restrict__ bs,
                                                 bf16* __restrict__ y) {
  int wid  = threadIdx.x >> 6;
  int lane = threadIdx.x & 63;
  int row  = blockIdx.x * 4 + wid;
  float4 v = ((const float4*)(x + (size_t)row * D_DIM))[lane];
  float s = v.x + v.y + v.z + v.w;
  #pragma unroll
  for (int m = 32; m; m >>= 1) s += __shfl_xor(s, m);
  float mu = s * (1.0f / 256.0f);
  float dx = v.x - mu, dy = v.y - mu, dz = v.z - mu, dw = v.w - mu;
  float s2 = dx * dx + dy * dy + dz * dz + dw * dw;
  #pragma unroll
  for (int m = 32; m; m >>= 1) s2 += __shfl_xor(s2, m);
  float rs = rsqrtf(s2 * (1.0f / 256.0f) + 1e-5f);
  float4 scv = ((const float4*)sc)[lane];
  float4 bsv = ((const float4*)bs)[lane];
  union { uint2 u; bf16 b[4]; } o;
  o.b[0] = (bf16)(dx * rs * scv.x + bsv.x);
  o.b[1] = (bf16)(dy * rs * scv.y + bsv.y);
  o.b[2] = (bf16)(dz * rs * scv.z + bsv.z);
  o.b[3] = (bf16)(dw * rs * scv.w + bsv.w);
  ((uint2*)y)[(size_t)row * 64 + lane] = o.u;
}

// ---------------- GEMM: A[M][256] bf16 @ Bt[N][256] bf16, m97 structure ----------------
// 128x128 tile, BK=64, global_load_lds(16B), XCD-grouped block mapping,
// LDS-transpose epilogue with vectorized 16B stores.
// MODE 0: C = qkvg bf16 [M][1024], sigmoid(+bg) on cols >= 768
// MODE 1: C = out  f32  [M][256], + bo
template <int MODE, int NCOLS, int NBBITS>
__global__ __launch_bounds__(256, 4) void gemm128(const bf16* __restrict__ A,
                                                  const bf16* __restrict__ Bt,
                                                  void* __restrict__ Cout,
                                                  const float* __restrict__ bias) {
  __shared__ __align__(16) bf16 smem[16384];   // As[0:8192) Bs[8192:16384); reused as C-stage
  bf16* As = smem;
  bf16* Bs = smem + 8192;
  const int tid  = threadIdx.x;
  const int wid  = tid >> 6;
  const int lane = tid & 63;
  // XCD-grouped decode: all NB n-blocks of one m-tile share bid%8 -> same XCD
  const int bid   = blockIdx.x;
  const int n_idx = (bid >> 3) & ((1 << NBBITS) - 1);
  const int m_idx = (bid & 7) | ((bid >> (3 + NBBITS)) << 3);
  const int m0 = m_idx * 128;
  const int n0 = n_idx * 128;
  const int lrow = lane & 15;
  const int lk   = (lane >> 4) * 8;
  const int wr = wid >> 1, wc = wid & 1;

  const int ln8 = lane >> 3;        // 0..7 (row within 8-row chunk)
  const int c8  = (lane & 7) * 8;   // col element within 64-col tile

  const bf16* Arow = A  + (size_t)m0 * 256 + c8;
  const bf16* Brow = Bt + (size_t)n0 * 256 + c8;

  f32x4 acc[4][4] = {};

  #pragma unroll
  for (int ks = 0; ks < 4; ++ks) {
    const int k0 = ks * 64;
    #pragma unroll
    for (int t = 0; t < 4; ++t) {
      int chunk = wid * 4 + t;
      int r = chunk * 8 + ln8;
      gl16(&As[chunk * 512], Arow + (size_t)r * 256 + k0);
      gl16(&Bs[chunk * 512], Brow + (size_t)r * 256 + k0);
    }
    __syncthreads();
    #pragma unroll
    for (int kk = 0; kk < 64; kk += 32) {
      bf16x8 av[4], bv[4];
      #pragma unroll
      for (int i = 0; i < 4; ++i)
        av[i] = *(const bf16x8*)(As + (wr * 64 + i * 16 + lrow) * 64 + kk + lk);
      #pragma unroll
      for (int j = 0; j < 4; ++j)
        bv[j] = *(const bf16x8*)(Bs + (wc * 64 + j * 16 + lrow) * 64 + kk + lk);
      #pragma unroll
      for (int i = 0; i < 4; ++i)
        #pragma unroll
        for (int j = 0; j < 4; ++j)
          acc[i][j] = __builtin_amdgcn_mfma_f32_16x16x32_bf16(av[i], bv[j], acc[i][j], 0, 0, 0);
    }
    __syncthreads();   // reads done before next stage / before epilogue reuse
  }

  const int rb = (lane >> 4) * 4;          // acc row-base within 16-row fragment
  const int xorv = rb << 2;                // {0,16,32,48} element XOR granule

  if (MODE == 0) {
    const bool isg = (n0 >= 768);
    float bgv[4];
    if (isg) {
      #pragma unroll
      for (int j = 0; j < 4; ++j) bgv[j] = bias[n0 - 768 + wc * 64 + j * 16 + lrow];
    }
    // dump C tile (bf16, 32KB) into smem with granule XOR
    #pragma unroll
    for (int i = 0; i < 4; ++i)
      #pragma unroll
      for (int j = 0; j < 4; ++j) {
        int col = wc * 64 + j * 16 + lrow;
        #pragma unroll
        for (int r = 0; r < 4; ++r) {
          int row = wr * 64 + i * 16 + rb + r;
          float v = acc[i][j][r];
          if (isg) { v += bgv[j]; v = 1.0f / (1.0f + __expf(-v)); }
          smem[row * 128 + (col ^ xorv)] = (bf16)v;
        }
      }
    __syncthreads();
    // coalesced 16B stores: 128 rows x 16 slots
    #pragma unroll
    for (int p = 0; p < 8; ++p) {
      int chunk = p * 256 + tid;
      int row = chunk >> 4, slot8 = (chunk & 15) * 8;
      int rx = (row & 12) << 2;
      *(uint4*)((bf16*)Cout + (size_t)(m0 + row) * NCOLS + n0 + slot8) =
          *(const uint4*)(smem + row * 128 + (slot8 ^ rx));
    }
  } else {
    // f32 epilogue in two half-tile passes (32KB each)
    float* smf = (float*)smem;
    float bov[4];
    #pragma unroll
    for (int j = 0; j < 4; ++j) bov[j] = bias[n0 + wc * 64 + j * 16 + lrow];
    #pragma unroll
    for (int half = 0; half < 2; ++half) {
      if (half) __syncthreads();   // (first sync already done after last MFMA)
      #pragma unroll
      for (int i2 = 0; i2 < 2; ++i2) {
        int i = half * 2 + i2;
        #pragma unroll
        for (int j = 0; j < 4; ++j) {
          int col = wc * 64 + j * 16 + lrow;
          #pragma unroll
          for (int r = 0; r < 4; ++r) {
            int crow = wr * 32 + i2 * 16 + rb + r;
            smf[crow * 128 + (col ^ xorv)] = acc[i][j][r] + bov[j];
          }
        }
      }
      __syncthreads();
      #pragma unroll
      for (int p = 0; p < 8; ++p) {
        int chunk = p * 256 + tid;
        int crow = chunk >> 5, slot = (chunk & 31) * 4;
        int rx = (crow & 12) << 2;
        int grow = m0 + (crow >> 5) * 64 + half * 32 + (crow & 31);
        *(uint4*)((float*)Cout + (size_t)grow * NCOLS + n0 + slot) =
            *(const uint4*)(smf + crow * 128 + (slot ^ rx));
      }
    }
  }
}

// ---------------- K3: attention per (residue, head) ----------------
// qkvg row = s*L + res, cols: q[0:256) k[256:512) v[512:768) g[768:1024), col=h*32+c
__global__ __launch_bounds__(256) void attn_kernel(const bf16* __restrict__ qkvg,
                                                   bf16* __restrict__ obuf) {
  __shared__ __align__(16) bf16 q_lds[128 * 40];
  __shared__ __align__(16) bf16 k_lds[128 * 40];
  __shared__ __align__(16) bf16 vt_lds[32 * 136];
  __shared__ __align__(16) bf16 p_lds[128 * 136];
  // XCD-grouped: 8 heads of one residue share an XCD (L2 line sharing on obuf)
  int bid = blockIdx.x;
  int h   = (bid >> 3) & 7;
  int res = (bid & 7) | ((bid >> 6) << 3);
  int tid = threadIdx.x;
  size_t base = (size_t)res * NQ + h * 32;

  // stage Q, K (row-major, padded) and V transposed
  for (int idx = tid; idx < 128 * 4; idx += 256) {
    int s = idx >> 2, c = (idx & 3) * 8;
    size_t g = (size_t)s * L_DIM * NQ + base + c;
    *(uint4*)(&q_lds[s * 40 + c]) = *(const uint4*)(qkvg + g);
    *(uint4*)(&k_lds[s * 40 + c]) = *(const uint4*)(qkvg + g + 256);
  }
  for (int idx = tid; idx < 128 * 4; idx += 256) {
    int t = idx >> 2, c = (idx & 3) * 8;
    union { uint4 u; bf16 e[8]; } v;
    v.u = *(const uint4*)(qkvg + (size_t)t * L_DIM * NQ + base + 512 + c);
    #pragma unroll
    for (int j = 0; j < 8; j++) vt_lds[(c + j) * 136 + t] = v.e[j];
  }
  __syncthreads();

  int wid = tid >> 6, lane = tid & 63;
  int lrow = lane & 15, lk = (lane >> 4) * 8;
  int s0 = wid * 32;

  // QK^T: per wave 32 rows x 128 cols
  f32x4 sc[2][8] = {};
  bf16x8 a0 = *(const bf16x8*)(&q_lds[(s0 + lrow) * 40 + lk]);
  bf16x8 a1 = *(const bf16x8*)(&q_lds[(s0 + 16 + lrow) * 40 + lk]);
  #pragma unroll
  for (int tc = 0; tc < 8; tc++) {
    bf16x8 b = *(const bf16x8*)(&k_lds[(tc * 16 + lrow) * 40 + lk]);
    sc[0][tc] = __builtin_amdgcn_mfma_f32_16x16x32_bf16(a0, b, sc[0][tc], 0, 0, 0);
    sc[1][tc] = __builtin_amdgcn_mfma_f32_16x16x32_bf16(a1, b, sc[1][tc], 0, 0, 0);
  }
  const float scale = 0.17677669529663687f; // 1/sqrt(32)
  #pragma unroll
  for (int i = 0; i < 2; i++)
    #pragma unroll
    for (int tc = 0; tc < 8; tc++) sc[i][tc] *= scale;

  // softmax over t (cols): row s lives in one 16-lane group at reg r
  #pragma unroll
  for (int tr = 0; tr < 2; tr++)
    #pragma unroll
    for (int r = 0; r < 4; r++) {
      float m = -1e30f;
      #pragma unroll
      for (int tc = 0; tc < 8; tc++) m = fmaxf(m, sc[tr][tc][r]);
      #pragma unroll
      for (int msk = 8; msk; msk >>= 1) m = fmaxf(m, __shfl_xor(m, msk));
      float ssum = 0.f;
      #pragma unroll
      for (int tc = 0; tc < 8; tc++) {
        float p = __expf(sc[tr][tc][r] - m);
        sc[tr][tc][r] = p;
        ssum += p;
      }
      #pragma unroll
      for (int msk = 8; msk; msk >>= 1) ssum += __shfl_xor(ssum, msk);
      float inv = 1.0f / ssum;
      int prow = s0 + tr * 16 + (lane >> 4) * 4 + r;
      #pragma unroll
      for (int tc = 0; tc < 8; tc++)
        p_lds[prow * 136 + tc * 16 + lrow] = (bf16)(sc[tr][tc][r] * inv);
    }
  __syncthreads();

  // PV: per wave 32 rows x 32 cols, K=128
  f32x4 oc[2][2] = {};
  #pragma unroll
  for (int kc = 0; kc < 4; kc++) {
    bf16x8 pa0 = *(const bf16x8*)(&p_lds[(s0 + lrow) * 136 + kc * 32 + lk]);
    bf16x8 pa1 = *(const bf16x8*)(&p_lds[(s0 + 16 + lrow) * 136 + kc * 32 + lk]);
    bf16x8 b0  = *(const bf16x8*)(&vt_lds[lrow * 136 + kc * 32 + lk]);
    bf16x8 b1  = *(const bf16x8*)(&vt_lds[(16 + lrow) * 136 + kc * 32 + lk]);
    oc[0][0] = __builtin_amdgcn_mfma_f32_16x16x32_bf16(pa0, b0, oc[0][0], 0, 0, 0);
    oc[0][1] = __builtin_amdgcn_mfma_f32_16x16x32_bf16(pa0, b1, oc[0][1], 0, 0, 0);
    oc[1][0] = __builtin_amdgcn_mfma_f32_16x16x32_bf16(pa1, b0, oc[1][0], 0, 0, 0);
    oc[1][1] = __builtin_amdgcn_mfma_f32_16x16x32_bf16(pa1, b1, oc[1][1], 0, 0, 0);
  }

  // dump raw O into own P-rows (no barrier needed: each wave overwrites only
  // rows it alone reads; all its PV reads of those rows precede the writes)
  int rbase = (lane >> 4) * 4;
  #pragma unroll
  for (int i = 0; i < 2; i++)
    #pragma unroll
    for (int j = 0; j < 2; j++)
      #pragma unroll
      for (int r = 0; r < 4; r++) {
        int srow = s0 + i * 16 + rbase + r;
        p_lds[srow * 136 + j * 16 + lrow] = (bf16)oc[i][j][r];
      }
  __syncthreads();

  // gated, vectorized store: 128 rows x 32 cols -> 512 16B chunks, 2/thread
  #pragma unroll
  for (int p = 0; p < 2; p++) {
    int chunk = p * 256 + tid;
    int srow = chunk >> 2, slot = (chunk & 3) * 8;
    bf16x8 g8 = *(const bf16x8*)(qkvg + (size_t)srow * L_DIM * NQ + base + 768 + slot);
    bf16x8 o8 = *(const bf16x8*)(&p_lds[srow * 136 + slot]);
    bf16x8 r8;
    #pragma unroll
    for (int u = 0; u < 8; u++) r8[u] = (bf16)((float)o8[u] * (float)g8[u]);
    *(uint4*)(obuf + ((size_t)srow * L_DIM + res) * 256 + h * 32 + slot) = *(uint4*)&r8;
  }
}

// ---------------- launch ----------------
extern "C" void kernel_launch(void* const* d_in, const int* in_sizes, int n_in,
                              void* d_out, int out_size, void* d_ws, size_t ws_size,
                              hipStream_t stream) {
  const float* msa      = (const float*)d_in[0];
  const float* ln_scale = (const float*)d_in[1];
  const float* ln_bias  = (const float*)d_in[2];
  const float* wq       = (const float*)d_in[3];
  const float* wk       = (const float*)d_in[4];
  const float* wv       = (const float*)d_in[5];
  const float* wg       = (const float*)d_in[6];
  const float* bg       = (const float*)d_in[7];
  const float* wo       = (const float*)d_in[8];
  const float* bo       = (const float*)d_in[9];
  float* out = (float*)d_out;

  char* ws = (char*)d_ws;
  bf16* wcat_t = (bf16*)ws;                                  // 512 KB
  bf16* wo_t   = (bf16*)(ws + 524288);                       // 128 KB
  bf16* qkvg   = (bf16*)(ws + 655360);                       // 128 MB
  bf16* obuf   = (bf16*)(ws + 655360 + 134217728ULL);        // 32 MB
  bf16* x_ln   = (bf16*)d_out;                               // 32 MB scratch inside out (dead before final GEMM)

  pack_weights<<<dim3(1280), dim3(256), 0, stream>>>(wq, wk, wv, wg, wo, wcat_t, wo_t);
  ln_kernel<<<dim3(65536 / 4), dim3(256), 0, stream>>>(msa, ln_scale, ln_bias, x_ln);
  gemm128<0, 1024, 3><<<dim3(4096), dim3(256), 0, stream>>>(x_ln, wcat_t, (void*)qkvg, bg);
  attn_kernel<<<dim3(4096), dim3(256), 0, stream>>>(qkvg, obuf);
  gemm128<1, 256, 1><<<dim3(1024), dim3(256), 0, stream>>>(obuf, wo_t, (void*)out, bo);
}

// Round 4
// 164.369 us; speedup vs baseline: 1.7397x; 1.0106x over previous
//
#include <hip/hip_runtime.h>
#include <hip/hip_bf16.h>

typedef __bf16 bf16;
typedef __bf16 bf16x8 __attribute__((ext_vector_type(8)));
typedef float f32x4 __attribute__((ext_vector_type(4)));

#define S_DIM 128
#define L_DIM 512
#define D_DIM 256
#define NQ    1024   // concatenated q|k|v|g columns

// async global->LDS, 16B per lane; lds must be the wave-uniform base
__device__ __forceinline__ void gl16(void* lds, const void* g) {
  __builtin_amdgcn_global_load_lds((const __attribute__((address_space(1))) void*)g,
                                   (__attribute__((address_space(3))) void*)lds,
                                   16, 0, 0);
}

// ---------------- K0: pack weights to bf16, transposed to N-major ----------------
__global__ void pack_weights(const float* __restrict__ wq, const float* __restrict__ wk,
                             const float* __restrict__ wv, const float* __restrict__ wg,
                             const float* __restrict__ wo,
                             bf16* __restrict__ wcat_t, bf16* __restrict__ wo_t) {
  int idx = blockIdx.x * 256 + threadIdx.x;
  const int total1 = NQ * D_DIM; // WcatT [1024][256]
  if (idx < total1) {
    int j = idx >> 8;      // output column 0..1023
    int d = idx & 255;     // k index
    const float* w = (j < 256) ? wq : (j < 512) ? wk : (j < 768) ? wv : wg;
    wcat_t[idx] = (bf16)w[d * 256 + (j & 255)];
  } else {
    int i2 = idx - total1; // woT [256][256]: woT[d][hc] = wo[hc][d]
    if (i2 < D_DIM * D_DIM) {
      int dcol = i2 >> 8, k = i2 & 255;
      wo_t[i2] = (bf16)wo[k * 256 + dcol];
    }
  }
}

// ---------------- K1: LayerNorm, one wave per row, write bf16 ----------------
__global__ __launch_bounds__(256) void ln_kernel(const float* __restrict__ x,
                                                 const float* __restrict__ sc,
                                                 const float* __restrict__ bs,
                                                 bf16* __restrict__ y) {
  int wid  = threadIdx.x >> 6;
  int lane = threadIdx.x & 63;
  int row  = blockIdx.x * 4 + wid;
  float4 v = ((const float4*)(x + (size_t)row * D_DIM))[lane];
  float s = v.x + v.y + v.z + v.w;
  #pragma unroll
  for (int m = 32; m; m >>= 1) s += __shfl_xor(s, m);
  float mu = s * (1.0f / 256.0f);
  float dx = v.x - mu, dy = v.y - mu, dz = v.z - mu, dw = v.w - mu;
  float s2 = dx * dx + dy * dy + dz * dz + dw * dw;
  #pragma unroll
  for (int m = 32; m; m >>= 1) s2 += __shfl_xor(s2, m);
  float rs = rsqrtf(s2 * (1.0f / 256.0f) + 1e-5f);
  float4 scv = ((const float4*)sc)[lane];
  float4 bsv = ((const float4*)bs)[lane];
  union { uint2 u; bf16 b[4]; } o;
  o.b[0] = (bf16)(dx * rs * scv.x + bsv.x);
  o.b[1] = (bf16)(dy * rs * scv.y + bsv.y);
  o.b[2] = (bf16)(dz * rs * scv.z + bsv.z);
  o.b[3] = (bf16)(dw * rs * scv.w + bsv.w);
  ((uint2*)y)[(size_t)row * 64 + lane] = o.u;
}

// swizzled LDS fragment read: logical (row, k-elem) in a [*][64] bf16 tile,
// physical byte = (row*128 + k*2) ^ ((row&7)<<4)
__device__ __forceinline__ bf16x8 lds_swz(const bf16* base, int row, int k) {
  return *(const bf16x8*)((const char*)base + ((((row << 6) + k) << 1) ^ ((row & 7) << 4)));
}

// ---------------- K2: QKVG GEMM: A[M][256] bf16 @ Bt[1024][256] bf16 ----------------
// 128x128 tile, BK=64, global_load_lds(16B) with pre-swizzled source (conflict-free
// ds_read_b128), XCD-grouped block mapping, LDS-transpose epilogue, sigmoid on g cols.
__global__ __launch_bounds__(256, 4) void gemm_qkvg(const bf16* __restrict__ A,
                                                    const bf16* __restrict__ Bt,
                                                    bf16* __restrict__ Cout,
                                                    const float* __restrict__ bias) {
  __shared__ __align__(16) bf16 smem[16384];   // As[0:8192) Bs[8192:16384); reused as C-stage
  bf16* As = smem;
  bf16* Bs = smem + 8192;
  const int tid  = threadIdx.x;
  const int wid  = tid >> 6;
  const int lane = tid & 63;
  // XCD-grouped decode: all 8 n-blocks of one m-tile share bid%8 -> same XCD
  const int bid   = blockIdx.x;
  const int n_idx = (bid >> 3) & 7;
  const int m_idx = (bid & 7) | ((bid >> 6) << 3);
  const int m0 = m_idx * 128;
  const int n0 = n_idx * 128;
  const int lrow = lane & 15;
  const int lk   = (lane >> 4) * 8;
  const int wr = wid >> 1, wc = wid & 1;

  const int ln8 = lane >> 3;                    // row within 8-row chunk
  const int c8  = ((lane & 7) ^ ln8) * 8;       // pre-swizzled source 16B slot

  const bf16* Arow = A  + (size_t)m0 * 256 + c8;
  const bf16* Brow = Bt + (size_t)n0 * 256 + c8;

  f32x4 acc[4][4] = {};

  #pragma unroll
  for (int ks = 0; ks < 4; ++ks) {
    const int k0 = ks * 64;
    #pragma unroll
    for (int t = 0; t < 4; ++t) {
      int chunk = wid * 4 + t;
      int r = chunk * 8 + ln8;
      gl16(&As[chunk * 512], Arow + (size_t)r * 256 + k0);
      gl16(&Bs[chunk * 512], Brow + (size_t)r * 256 + k0);
    }
    __syncthreads();
    #pragma unroll
    for (int kk = 0; kk < 64; kk += 32) {
      bf16x8 av[4], bv[4];
      #pragma unroll
      for (int i = 0; i < 4; ++i)
        av[i] = lds_swz(As, wr * 64 + i * 16 + lrow, kk + lk);
      #pragma unroll
      for (int j = 0; j < 4; ++j)
        bv[j] = lds_swz(Bs, wc * 64 + j * 16 + lrow, kk + lk);
      #pragma unroll
      for (int i = 0; i < 4; ++i)
        #pragma unroll
        for (int j = 0; j < 4; ++j)
          acc[i][j] = __builtin_amdgcn_mfma_f32_16x16x32_bf16(av[i], bv[j], acc[i][j], 0, 0, 0);
    }
    __syncthreads();   // reads done before next stage / before epilogue reuse
  }

  const int rb = (lane >> 4) * 4;          // acc row-base within 16-row fragment
  const int xorv = rb << 2;                // {0,16,32,48} element XOR granule

  const bool isg = (n0 >= 768);
  float bgv[4];
  if (isg) {
    #pragma unroll
    for (int j = 0; j < 4; ++j) bgv[j] = bias[n0 - 768 + wc * 64 + j * 16 + lrow];
  }
  // dump C tile (bf16, 32KB) into smem with granule XOR
  #pragma unroll
  for (int i = 0; i < 4; ++i)
    #pragma unroll
    for (int j = 0; j < 4; ++j) {
      int col = wc * 64 + j * 16 + lrow;
      #pragma unroll
      for (int r = 0; r < 4; ++r) {
        int row = wr * 64 + i * 16 + rb + r;
        float v = acc[i][j][r];
        if (isg) { v += bgv[j]; v = 1.0f / (1.0f + __expf(-v)); }
        smem[row * 128 + (col ^ xorv)] = (bf16)v;
      }
    }
  __syncthreads();
  // coalesced 16B stores: 128 rows x 16 slots
  #pragma unroll
  for (int p = 0; p < 8; ++p) {
    int chunk = p * 256 + tid;
    int row = chunk >> 4, slot8 = (chunk & 15) * 8;
    int rx = (row & 12) << 2;
    *(uint4*)(Cout + (size_t)(m0 + row) * NQ + n0 + slot8) =
        *(const uint4*)(smem + row * 128 + (slot8 ^ rx));
  }
}

// ---------------- K3: fused attention + gate + output projection, per residue ----------
// Block = one residue (512 blocks), 512 threads (8 waves, 16 S-rows each).
// Per head h: stage Qh,Kh (gl16 linear [128][32]), V^T (reg), QK^T -> softmax (per-wave,
// P never crosses waves) -> PV -> gate -> o_scr; acc += o_h @ woT[h*32:+32,:]
// (heads = disjoint K-slices of the projection). Epilogue: banded f32 stores via LDS.
__global__ __launch_bounds__(512) void attn_proj(const bf16* __restrict__ qkvg,
                                                 const bf16* __restrict__ wo_t,
                                                 const float* __restrict__ bo,
                                                 float* __restrict__ out) {
  __shared__ __align__(16) bf16 q_s[128 * 32];    // Q slice; reused as gated-O (o_scr)
  __shared__ __align__(16) bf16 k_s[128 * 32];
  __shared__ __align__(16) bf16 vt_s[32 * 136];
  __shared__ __align__(16) char p_rg[34816];      // P[128][136]bf16 | w[256][32]bf16 | band[32][256]f32
  bf16*  p_s = (bf16*)p_rg;
  bf16*  w_s = (bf16*)p_rg;
  float* f_b = (float*)p_rg;

  const int tid  = threadIdx.x;
  const int wid  = tid >> 6;
  const int lane = tid & 63;
  const int lrow = lane & 15;
  const int lk   = (lane >> 4) * 8;
  const int rb   = (lane >> 4) * 4;
  const int res  = blockIdx.x;

  const int wm = wid >> 1;   // proj M band (0..3), rows wm*32..+31
  const int wn = wid & 1;    // proj N half (0..1), cols wn*128..+127
  const int s0 = wid * 16;   // attention rows for this wave

  float bov[8];
  #pragma unroll
  for (int j = 0; j < 8; ++j) bov[j] = bo[wn * 128 + j * 16 + lrow];

  f32x4 acc[2][8] = {};

  const int srow = (wid * 64 + lane) >> 2;   // staging row 0..127 (1 chunk/thread)
  const int sslot = lane & 3;

  for (int h = 0; h < 8; ++h) {
    const int hc0 = h * 32;
    // [A] stage Q,K (gl16, linear [128][32]) and V^T (reg scatter)
    {
      const bf16* src = qkvg + ((size_t)srow * L_DIM + res) * NQ + hc0 + sslot * 8;
      gl16(q_s + wid * 512, src);          // Q
      gl16(k_s + wid * 512, src + 256);    // K
      int row = tid >> 2, slot = tid & 3;
      union { uint4 u; bf16 e[8]; } v;
      v.u = *(const uint4*)(qkvg + ((size_t)row * L_DIM + res) * NQ + 512 + hc0 + slot * 8);
      #pragma unroll
      for (int j = 0; j < 8; ++j) vt_s[(slot * 8 + j) * 136 + row] = v.e[j];
    }
    __syncthreads();   // [B] staging visible

    // QK^T: this wave's 16 rows x 128 t
    f32x4 s8[8];
    {
      const f32x4 z = {0.f, 0.f, 0.f, 0.f};
      bf16x8 av = *(const bf16x8*)(q_s + (s0 + lrow) * 32 + lk);
      #pragma unroll
      for (int tc = 0; tc < 8; ++tc) {
        bf16x8 bv = *(const bf16x8*)(k_s + (tc * 16 + lrow) * 32 + lk);
        s8[tc] = __builtin_amdgcn_mfma_f32_16x16x32_bf16(av, bv, z, 0, 0, 0);
      }
    }
    const float scale = 0.17677669529663687f; // 1/sqrt(32)
    // softmax over t (in-lane over 8 regs + 16-lane-group shuffle), write P
    #pragma unroll
    for (int r = 0; r < 4; ++r) {
      float m = -1e30f;
      #pragma unroll
      for (int tc = 0; tc < 8; ++tc) m = fmaxf(m, s8[tc][r]);
      #pragma unroll
      for (int msk = 8; msk; msk >>= 1) m = fmaxf(m, __shfl_xor(m, msk));
      float pv[8], ssum = 0.f;
      #pragma unroll
      for (int tc = 0; tc < 8; ++tc) {
        float p = __expf((s8[tc][r] - m) * scale);
        pv[tc] = p; ssum += p;
      }
      #pragma unroll
      for (int msk = 8; msk; msk >>= 1) ssum += __shfl_xor(ssum, msk);
      float inv = 1.0f / ssum;
      int prow = s0 + rb + r;
      #pragma unroll
      for (int tc = 0; tc < 8; ++tc)
        p_s[prow * 136 + tc * 16 + lrow] = (bf16)(pv[tc] * inv);
    }

    // PV: own P rows x all V cols (K=128)
    f32x4 oc[2] = {};
    #pragma unroll
    for (int kc = 0; kc < 4; ++kc) {
      bf16x8 pa = *(const bf16x8*)(p_s + (s0 + lrow) * 136 + kc * 32 + lk);
      bf16x8 b0 = *(const bf16x8*)(vt_s + lrow * 136 + kc * 32 + lk);
      bf16x8 b1 = *(const bf16x8*)(vt_s + (16 + lrow) * 136 + kc * 32 + lk);
      oc[0] = __builtin_amdgcn_mfma_f32_16x16x32_bf16(pa, b0, oc[0], 0, 0, 0);
      oc[1] = __builtin_amdgcn_mfma_f32_16x16x32_bf16(pa, b1, oc[1], 0, 0, 0);
    }
    // raw O into o_scr (= q_s; own Q rows already consumed by own QK^T)
    #pragma unroll
    for (int cj = 0; cj < 2; ++cj)
      #pragma unroll
      for (int r = 0; r < 4; ++r)
        q_s[(s0 + rb + r) * 32 + cj * 16 + lrow] = (bf16)oc[cj][r];
    __syncthreads();   // [F] P fully consumed + o_scr written

    // [G] stage wo slice [256 d][32 c] into p region (gl16) + gate o_scr in place
    #pragma unroll
    for (int t = 0; t < 2; ++t) {
      int ch = t * 512 + wid * 64 + lane;
      int row = ch >> 2, slot = ch & 3;
      gl16((char*)p_rg + (t * 512 + wid * 64) * 16, wo_t + row * 256 + hc0 + slot * 8);
    }
    {
      int row = tid >> 2, slot = tid & 3;
      union { uint4 u; bf16 e[8]; } g, o;
      g.u = *(const uint4*)(qkvg + ((size_t)row * L_DIM + res) * NQ + 768 + hc0 + slot * 8);
      o.u = *(const uint4*)(q_s + row * 32 + slot * 8);
      #pragma unroll
      for (int j = 0; j < 8; ++j) o.e[j] = (bf16)((float)o.e[j] * (float)g.e[j]);
      *(uint4*)(q_s + row * 32 + slot * 8) = o.u;
    }
    __syncthreads();   // [H] w staged + o gated

    // [I] projection accumulate: out[128][256] += o_g[128][32] @ woT_h[256][32]^T
    {
      bf16x8 av0 = *(const bf16x8*)(q_s + (wm * 32 + lrow) * 32 + lk);
      bf16x8 av1 = *(const bf16x8*)(q_s + (wm * 32 + 16 + lrow) * 32 + lk);
      #pragma unroll
      for (int j = 0; j < 8; ++j) {
        bf16x8 bv = *(const bf16x8*)(w_s + (wn * 128 + j * 16 + lrow) * 32 + lk);
        acc[0][j] = __builtin_amdgcn_mfma_f32_16x16x32_bf16(av0, bv, acc[0][j], 0, 0, 0);
        acc[1][j] = __builtin_amdgcn_mfma_f32_16x16x32_bf16(av1, bv, acc[1][j], 0, 0, 0);
      }
    }
    __syncthreads();   // [J] w/p region + o_scr free for next head
  }

  // epilogue: 4 bands of 32 rows, f32 via p region, full-line coalesced stores
  #pragma unroll 1
  for (int b = 0; b < 4; ++b) {
    if (wm == b) {
      #pragma unroll
      for (int i = 0; i < 2; ++i)
        #pragma unroll
        for (int j = 0; j < 8; ++j)
          #pragma unroll
          for (int r = 0; r < 4; ++r) {
            int br = i * 16 + rb + r;
            int col = wn * 128 + j * 16 + lrow;
            f_b[br * 256 + (col ^ ((br & 12) << 2))] = acc[i][j][r] + bov[j];
          }
    }
    __syncthreads();
    #pragma unroll
    for (int u = 0; u < 4; ++u) {
      int ch = u * 512 + tid;
      int br = ch >> 6, slot = ch & 63;
      int phys = (slot * 4) ^ ((br & 12) << 2);
      *(uint4*)(out + ((size_t)(b * 32 + br) * L_DIM + res) * 256 + slot * 4) =
          *(const uint4*)(f_b + br * 256 + phys);
    }
    __syncthreads();
  }
}

// ---------------- launch ----------------
extern "C" void kernel_launch(void* const* d_in, const int* in_sizes, int n_in,
                              void* d_out, int out_size, void* d_ws, size_t ws_size,
                              hipStream_t stream) {
  const float* msa      = (const float*)d_in[0];
  const float* ln_scale = (const float*)d_in[1];
  const float* ln_bias  = (const float*)d_in[2];
  const float* wq       = (const float*)d_in[3];
  const float* wk       = (const float*)d_in[4];
  const float* wv       = (const float*)d_in[5];
  const float* wg       = (const float*)d_in[6];
  const float* bg       = (const float*)d_in[7];
  const float* wo       = (const float*)d_in[8];
  const float* bo       = (const float*)d_in[9];
  float* out = (float*)d_out;

  char* ws = (char*)d_ws;
  bf16* wcat_t = (bf16*)ws;                                  // 512 KB
  bf16* wo_t   = (bf16*)(ws + 524288);                       // 128 KB
  bf16* qkvg   = (bf16*)(ws + 655360);                       // 128 MB
  bf16* x_ln   = (bf16*)d_out;                               // 32 MB scratch in d_out (dead before attn_proj writes)

  pack_weights<<<dim3(1280), dim3(256), 0, stream>>>(wq, wk, wv, wg, wo, wcat_t, wo_t);
  ln_kernel<<<dim3(65536 / 4), dim3(256), 0, stream>>>(msa, ln_scale, ln_bias, x_ln);
  gemm_qkvg<<<dim3(4096), dim3(256), 0, stream>>>(x_ln, wcat_t, qkvg, bg);
  attn_proj<<<dim3(512), dim3(512), 0, stream>>>(qkvg, wo_t, bo, out);
}

// Round 5
// 156.892 us; speedup vs baseline: 1.8226x; 1.0477x over previous
//
#include <hip/hip_runtime.h>
#include <hip/hip_bf16.h>

typedef __bf16 bf16;
typedef __bf16 bf16x8 __attribute__((ext_vector_type(8)));
typedef float f32x4 __attribute__((ext_vector_type(4)));

#define S_DIM 128
#define L_DIM 512
#define D_DIM 256
#define NQ    1024   // concatenated q|k|v|g columns

// async global->LDS, 16B per lane; lds must be the wave-uniform base
__device__ __forceinline__ void gl16(void* lds, const void* g) {
  __builtin_amdgcn_global_load_lds((const __attribute__((address_space(1))) void*)g,
                                   (__attribute__((address_space(3))) void*)lds,
                                   16, 0, 0);
}

// ---------------- K0: pack weights to bf16, transposed to N-major ----------------
__global__ void pack_weights(const float* __restrict__ wq, const float* __restrict__ wk,
                             const float* __restrict__ wv, const float* __restrict__ wg,
                             const float* __restrict__ wo,
                             bf16* __restrict__ wcat_t, bf16* __restrict__ wo_t) {
  int idx = blockIdx.x * 256 + threadIdx.x;
  const int total1 = NQ * D_DIM; // WcatT [1024][256]
  if (idx < total1) {
    int j = idx >> 8;      // output column 0..1023
    int d = idx & 255;     // k index
    const float* w = (j < 256) ? wq : (j < 512) ? wk : (j < 768) ? wv : wg;
    wcat_t[idx] = (bf16)w[d * 256 + (j & 255)];
  } else {
    int i2 = idx - total1; // woT [256][256]: woT[d][hc] = wo[hc][d]
    if (i2 < D_DIM * D_DIM) {
      int dcol = i2 >> 8, k = i2 & 255;
      wo_t[i2] = (bf16)wo[k * 256 + dcol];
    }
  }
}

// ---------------- K1: LayerNorm, one wave per row, write bf16 ----------------
__global__ __launch_bounds__(256) void ln_kernel(const float* __restrict__ x,
                                                 const float* __restrict__ sc,
                                                 const float* __restrict__ bs,
                                                 bf16* __restrict__ y) {
  int wid  = threadIdx.x >> 6;
  int lane = threadIdx.x & 63;
  int row  = blockIdx.x * 4 + wid;
  float4 v = ((const float4*)(x + (size_t)row * D_DIM))[lane];
  float s = v.x + v.y + v.z + v.w;
  #pragma unroll
  for (int m = 32; m; m >>= 1) s += __shfl_xor(s, m);
  float mu = s * (1.0f / 256.0f);
  float dx = v.x - mu, dy = v.y - mu, dz = v.z - mu, dw = v.w - mu;
  float s2 = dx * dx + dy * dy + dz * dz + dw * dw;
  #pragma unroll
  for (int m = 32; m; m >>= 1) s2 += __shfl_xor(s2, m);
  float rs = rsqrtf(s2 * (1.0f / 256.0f) + 1e-5f);
  float4 scv = ((const float4*)sc)[lane];
  float4 bsv = ((const float4*)bs)[lane];
  union { uint2 u; bf16 b[4]; } o;
  o.b[0] = (bf16)(dx * rs * scv.x + bsv.x);
  o.b[1] = (bf16)(dy * rs * scv.y + bsv.y);
  o.b[2] = (bf16)(dz * rs * scv.z + bsv.z);
  o.b[3] = (bf16)(dw * rs * scv.w + bsv.w);
  ((uint2*)y)[(size_t)row * 64 + lane] = o.u;
}

// swizzled LDS fragment read: logical (row, k-elem) in a [*][64] bf16 tile,
// physical byte = (row*128 + k*2) ^ ((row&7)<<4)
__device__ __forceinline__ bf16x8 lds_swz(const bf16* base, int row, int k) {
  return *(const bf16x8*)((const char*)base + ((((row << 6) + k) << 1) ^ ((row & 7) << 4)));
}

// ---------------- K2: QKVG GEMM: A[M][256] bf16 @ Bt[1024][256] bf16 ----------------
// 128x128 tile, BK=64, global_load_lds(16B) with pre-swizzled source (conflict-free
// ds_read_b128), XCD-grouped block mapping, LDS-transpose epilogue, sigmoid on g cols.
__global__ __launch_bounds__(256, 4) void gemm_qkvg(const bf16* __restrict__ A,
                                                    const bf16* __restrict__ Bt,
                                                    bf16* __restrict__ Cout,
                                                    const float* __restrict__ bias) {
  __shared__ __align__(16) bf16 smem[16384];   // As[0:8192) Bs[8192:16384); reused as C-stage
  bf16* As = smem;
  bf16* Bs = smem + 8192;
  const int tid  = threadIdx.x;
  const int wid  = tid >> 6;
  const int lane = tid & 63;
  // XCD-grouped decode: all 8 n-blocks of one m-tile share bid%8 -> same XCD
  const int bid   = blockIdx.x;
  const int n_idx = (bid >> 3) & 7;
  const int m_idx = (bid & 7) | ((bid >> 6) << 3);
  const int m0 = m_idx * 128;
  const int n0 = n_idx * 128;
  const int lrow = lane & 15;
  const int lk   = (lane >> 4) * 8;
  const int wr = wid >> 1, wc = wid & 1;

  const int ln8 = lane >> 3;                    // row within 8-row chunk
  const int c8  = ((lane & 7) ^ ln8) * 8;       // pre-swizzled source 16B slot

  const bf16* Arow = A  + (size_t)m0 * 256 + c8;
  const bf16* Brow = Bt + (size_t)n0 * 256 + c8;

  f32x4 acc[4][4] = {};

  #pragma unroll
  for (int ks = 0; ks < 4; ++ks) {
    const int k0 = ks * 64;
    #pragma unroll
    for (int t = 0; t < 4; ++t) {
      int chunk = wid * 4 + t;
      int r = chunk * 8 + ln8;
      gl16(&As[chunk * 512], Arow + (size_t)r * 256 + k0);
      gl16(&Bs[chunk * 512], Brow + (size_t)r * 256 + k0);
    }
    __syncthreads();
    #pragma unroll
    for (int kk = 0; kk < 64; kk += 32) {
      bf16x8 av[4], bv[4];
      #pragma unroll
      for (int i = 0; i < 4; ++i)
        av[i] = lds_swz(As, wr * 64 + i * 16 + lrow, kk + lk);
      #pragma unroll
      for (int j = 0; j < 4; ++j)
        bv[j] = lds_swz(Bs, wc * 64 + j * 16 + lrow, kk + lk);
      #pragma unroll
      for (int i = 0; i < 4; ++i)
        #pragma unroll
        for (int j = 0; j < 4; ++j)
          acc[i][j] = __builtin_amdgcn_mfma_f32_16x16x32_bf16(av[i], bv[j], acc[i][j], 0, 0, 0);
    }
    __syncthreads();   // reads done before next stage / before epilogue reuse
  }

  const int rb = (lane >> 4) * 4;          // acc row-base within 16-row fragment
  const int xorv = rb << 2;                // {0,16,32,48} element XOR granule

  const bool isg = (n0 >= 768);
  float bgv[4];
  if (isg) {
    #pragma unroll
    for (int j = 0; j < 4; ++j) bgv[j] = bias[n0 - 768 + wc * 64 + j * 16 + lrow];
  }
  // dump C tile (bf16, 32KB) into smem with granule XOR
  #pragma unroll
  for (int i = 0; i < 4; ++i)
    #pragma unroll
    for (int j = 0; j < 4; ++j) {
      int col = wc * 64 + j * 16 + lrow;
      #pragma unroll
      for (int r = 0; r < 4; ++r) {
        int row = wr * 64 + i * 16 + rb + r;
        float v = acc[i][j][r];
        if (isg) { v += bgv[j]; v = 1.0f / (1.0f + __expf(-v)); }
        smem[row * 128 + (col ^ xorv)] = (bf16)v;
      }
    }
  __syncthreads();
  // coalesced 16B stores: 128 rows x 16 slots
  #pragma unroll
  for (int p = 0; p < 8; ++p) {
    int chunk = p * 256 + tid;
    int row = chunk >> 4, slot8 = (chunk & 15) * 8;
    int rx = (row & 12) << 2;
    *(uint4*)(Cout + (size_t)(m0 + row) * NQ + n0 + slot8) =
        *(const uint4*)(smem + row * 128 + (slot8 ^ rx));
  }
}

// ---------------- K3: fused attention + gate + output projection, per residue ----------
// Block = residue (512 blocks), 512 threads = 8 waves. WAVE = HEAD for attention:
// zero block-wide barriers in the attention phase. K-frags direct from global (held in
// regs); V^T staged wave-private; per-s-strip: QK^T -> in-reg softmax -> wave-private
// P-transpose (half-t, 2.3KB) -> PV; raw O -> shared o_full. One barrier, then K=256
// projection with gate fused into A-frag build and wo staged in 2 swizzled halves.
__global__ __launch_bounds__(512) void attn_proj(const bf16* __restrict__ qkvg,
                                                 const bf16* __restrict__ wo_t,
                                                 const float* __restrict__ bo,
                                                 float* __restrict__ out) {
  // vt [8 waves][32][136] bf16 : 69632 B   (V^T per head, wave-private)
  // Pp [8 waves][16][72]  bf16 : 18432 B   (P strip transpose, half-t, wave-private)
  // of [128][264]         bf16 : 67584 B   (raw O, shared)       total 155648 B
  // overlays: wS (64KB, proj weights) on bytes [0,65536) after barrier;
  //           fb (f32 band, 33792 B) on bytes [0,33792) in the epilogue.
  __shared__ __align__(16) char smem[155648];
  const int tid  = threadIdx.x;
  const int wid  = tid >> 6;
  const int lane = tid & 63;
  const int lrow = lane & 15;
  const int lkg  = lane >> 4;
  const int lk   = lkg * 8;
  const int rb   = lkg * 4;
  const int res  = blockIdx.x;
  const int hc0  = wid * 32;     // this wave's head columns

  bf16* vw = (bf16*)smem + wid * (32 * 136);
  bf16* pw = (bf16*)(smem + 69632) + wid * (16 * 72);
  bf16* of = (bf16*)(smem + 88064);

  // ---- stage V^T for own head (wave-private, no barrier) ----
  {
    int t0 = lane >> 2, cs = (lane & 3) * 8;
    #pragma unroll
    for (int pass = 0; pass < 8; ++pass) {
      int t = pass * 16 + t0;
      union { uint4 u; bf16 e[8]; } v;
      v.u = *(const uint4*)(qkvg + (size_t)(t * L_DIM + res) * NQ + 512 + hc0 + cs);
      #pragma unroll
      for (int j = 0; j < 8; ++j) vw[(cs + j) * 136 + t] = v.e[j];
    }
  }

  // ---- K fragments, held in registers for the whole attention phase ----
  bf16x8 kf[8];
  #pragma unroll
  for (int tt = 0; tt < 8; ++tt)
    kf[tt] = *(const bf16x8*)(qkvg + (size_t)((tt * 16 + lrow) * L_DIM + res) * NQ + 256 + hc0 + lk);

  const float scale = 0.17677669529663687f; // 1/sqrt(32)
  const f32x4 z = {0.f, 0.f, 0.f, 0.f};

  // ---- attention: 8 strips of 16 s-rows, no block barriers ----
  for (int st = 0; st < 8; ++st) {
    bf16x8 qf = *(const bf16x8*)(qkvg + (size_t)((st * 16 + lrow) * L_DIM + res) * NQ + hc0 + lk);
    f32x4 sc[8];
    #pragma unroll
    for (int tt = 0; tt < 8; ++tt)
      sc[tt] = __builtin_amdgcn_mfma_f32_16x16x32_bf16(qf, kf[tt], z, 0, 0, 0);

    // softmax over t for rows rb+r (in-lane 8 regs + 16-lane-group shuffles)
    #pragma unroll
    for (int r = 0; r < 4; ++r) {
      float m = sc[0][r];
      #pragma unroll
      for (int tc = 1; tc < 8; ++tc) m = fmaxf(m, sc[tc][r]);
      #pragma unroll
      for (int msk = 8; msk; msk >>= 1) m = fmaxf(m, __shfl_xor(m, msk));
      float pv[8], ssum = 0.f;
      #pragma unroll
      for (int tc = 0; tc < 8; ++tc) {
        float p = __expf((sc[tc][r] - m) * scale);
        pv[tc] = p; ssum += p;
      }
      #pragma unroll
      for (int msk = 8; msk; msk >>= 1) ssum += __shfl_xor(ssum, msk);
      float inv = 1.0f / ssum;
      #pragma unroll
      for (int tc = 0; tc < 8; ++tc) sc[tc][r] = pv[tc] * inv;
    }

    // PV in two t-halves through the wave-private 16x64 transpose buffer
    f32x4 oc[2] = {z, z};
    #pragma unroll
    for (int hf = 0; hf < 2; ++hf) {
      #pragma unroll
      for (int tc = 0; tc < 4; ++tc)
        #pragma unroll
        for (int r = 0; r < 4; ++r)
          pw[(rb + r) * 72 + tc * 16 + lrow] = (bf16)sc[hf * 4 + tc][r];
      #pragma unroll
      for (int kc = 0; kc < 2; ++kc) {
        bf16x8 pa = *(const bf16x8*)(pw + lrow * 72 + kc * 32 + lk);
        #pragma unroll
        for (int ct = 0; ct < 2; ++ct) {
          bf16x8 bv = *(const bf16x8*)(vw + (ct * 16 + lrow) * 136 + hf * 64 + kc * 32 + lk);
          oc[ct] = __builtin_amdgcn_mfma_f32_16x16x32_bf16(pa, bv, oc[ct], 0, 0, 0);
        }
      }
    }
    // raw O strip -> shared o_full (this wave's head columns only)
    #pragma unroll
    for (int ct = 0; ct < 2; ++ct)
      #pragma unroll
      for (int r = 0; r < 4; ++r)
        of[(st * 16 + rb + r) * 264 + hc0 + ct * 16 + lrow] = (bf16)oc[ct][r];
  }
  __syncthreads();   // o_full complete; vt/Pp regions now dead

  // ---- projection: out[128][256] = (o*g)[128][256] @ woT[256][256]^T + bo ----
  const int pbase = (wid >> 1) * 32;   // this wave's 32 output rows
  const int pn    = wid & 1;           // 64-col group within each 128-col half

  // gated A-fragments (16), reused across both N-halves
  bf16x8 af[2][8];
  #pragma unroll
  for (int mt = 0; mt < 2; ++mt) {
    int s = pbase + mt * 16 + lrow;
    #pragma unroll
    for (int kt = 0; kt < 8; ++kt) {
      bf16x8 o8 = *(const bf16x8*)(of + s * 264 + kt * 32 + lk);
      bf16x8 g8 = *(const bf16x8*)(qkvg + (size_t)(s * L_DIM + res) * NQ + 768 + kt * 32 + lk);
      bf16x8 rr;
      #pragma unroll
      for (int j = 0; j < 8; ++j) rr[j] = (bf16)((float)o8[j] * (float)g8[j]);
      af[mt][kt] = rr;
    }
  }

  float bov[2][4];
  #pragma unroll
  for (int hf = 0; hf < 2; ++hf)
    #pragma unroll
    for (int nt = 0; nt < 4; ++nt)
      bov[hf][nt] = bo[hf * 128 + pn * 64 + nt * 16 + lrow];

  bf16* wS = (bf16*)smem;
  f32x4 acc[2][2][4] = {};   // [half][mt][nt]
  #pragma unroll
  for (int hf = 0; hf < 2; ++hf) {
    // stage wo half [128 d][256 hc] with pre-swizzled source (32 16B-slots/row, XOR d&7)
    #pragma unroll
    for (int pass = 0; pass < 8; ++pass) {
      int ch = pass * 512 + tid;
      int dl = ch >> 5, sl = ch & 31;
      gl16((char*)wS + (pass * 512 + wid * 64) * 16,
           wo_t + (size_t)(hf * 128 + dl) * 256 + (sl ^ (dl & 7)) * 8);
    }
    __syncthreads();
    #pragma unroll
    for (int kt = 0; kt < 8; ++kt)
      #pragma unroll
      for (int nt = 0; nt < 4; ++nt) {
        int dl = pn * 64 + nt * 16 + lrow;
        bf16x8 bw = *(const bf16x8*)((char*)wS + dl * 512 + (((kt * 4 + lkg) ^ (dl & 7)) * 16));
        acc[hf][0][nt] = __builtin_amdgcn_mfma_f32_16x16x32_bf16(af[0][kt], bw, acc[hf][0][nt], 0, 0, 0);
        acc[hf][1][nt] = __builtin_amdgcn_mfma_f32_16x16x32_bf16(af[1][kt], bw, acc[hf][1][nt], 0, 0, 0);
      }
    __syncthreads();   // wS reads done before overwrite (next half / fb)
  }

  // ---- epilogue: 4 bands of 32 rows via f32 LDS, full-line coalesced stores ----
  float* fb = (float*)smem;
  #pragma unroll 1
  for (int b = 0; b < 4; ++b) {
    if ((wid >> 1) == b) {
      #pragma unroll
      for (int hf = 0; hf < 2; ++hf)
        #pragma unroll
        for (int mt = 0; mt < 2; ++mt)
          #pragma unroll
          for (int nt = 0; nt < 4; ++nt)
            #pragma unroll
            for (int r = 0; r < 4; ++r)
              fb[(mt * 16 + rb + r) * 264 + hf * 128 + pn * 64 + nt * 16 + lrow] =
                  acc[hf][mt][nt][r] + bov[hf][nt];
    }
    __syncthreads();
    #pragma unroll
    for (int u = 0; u < 4; ++u) {
      int ch = u * 512 + tid;
      int row = ch >> 6, c4 = (ch & 63) * 4;
      *(uint4*)(out + (size_t)((b * 32 + row) * L_DIM + res) * 256 + c4) =
          *(const uint4*)(fb + row * 264 + c4);
    }
    __syncthreads();
  }
}

// ---------------- launch ----------------
extern "C" void kernel_launch(void* const* d_in, const int* in_sizes, int n_in,
                              void* d_out, int out_size, void* d_ws, size_t ws_size,
                              hipStream_t stream) {
  const float* msa      = (const float*)d_in[0];
  const float* ln_scale = (const float*)d_in[1];
  const float* ln_bias  = (const float*)d_in[2];
  const float* wq       = (const float*)d_in[3];
  const float* wk       = (const float*)d_in[4];
  const float* wv       = (const float*)d_in[5];
  const float* wg       = (const float*)d_in[6];
  const float* bg       = (const float*)d_in[7];
  const float* wo       = (const float*)d_in[8];
  const float* bo       = (const float*)d_in[9];
  float* out = (float*)d_out;

  char* ws = (char*)d_ws;
  bf16* wcat_t = (bf16*)ws;                                  // 512 KB
  bf16* wo_t   = (bf16*)(ws + 524288);                       // 128 KB
  bf16* qkvg   = (bf16*)(ws + 655360);                       // 128 MB
  bf16* x_ln   = (bf16*)d_out;                               // 32 MB scratch in d_out (dead before attn_proj writes)

  pack_weights<<<dim3(1280), dim3(256), 0, stream>>>(wq, wk, wv, wg, wo, wcat_t, wo_t);
  ln_kernel<<<dim3(65536 / 4), dim3(256), 0, stream>>>(msa, ln_scale, ln_bias, x_ln);
  gemm_qkvg<<<dim3(4096), dim3(256), 0, stream>>>(x_ln, wcat_t, qkvg, bg);
  attn_proj<<<dim3(512), dim3(512), 0, stream>>>(qkvg, wo_t, bo, out);
}

// Round 6
// 156.119 us; speedup vs baseline: 1.8317x; 1.0050x over previous
//
#include <hip/hip_runtime.h>
#include <hip/hip_bf16.h>

typedef __bf16 bf16;
typedef __bf16 bf16x8 __attribute__((ext_vector_type(8)));
typedef float f32x4 __attribute__((ext_vector_type(4)));

#define S_DIM 128
#define L_DIM 512
#define D_DIM 256
#define NQ    1024

// async global->LDS, 16B per lane; lds must be the wave-uniform base
__device__ __forceinline__ void gl16(void* lds, const void* g) {
  __builtin_amdgcn_global_load_lds((const __attribute__((address_space(1))) void*)g,
                                   (__attribute__((address_space(3))) void*)lds,
                                   16, 0, 0);
}

// ---------------- K0: pack weights to bf16, transposed to N-major ----------------
__global__ void pack_weights(const float* __restrict__ wq, const float* __restrict__ wk,
                             const float* __restrict__ wv, const float* __restrict__ wg,
                             const float* __restrict__ wo,
                             bf16* __restrict__ wcat_t, bf16* __restrict__ wo_t) {
  int idx = blockIdx.x * 256 + threadIdx.x;
  const int total1 = NQ * D_DIM; // WcatT [1024][256]
  if (idx < total1) {
    int j = idx >> 8;      // output column 0..1023
    int d = idx & 255;     // k index
    const float* w = (j < 256) ? wq : (j < 512) ? wk : (j < 768) ? wv : wg;
    wcat_t[idx] = (bf16)w[d * 256 + (j & 255)];
  } else {
    int i2 = idx - total1; // woT [256][256]: woT[d][hc] = wo[hc][d]
    if (i2 < D_DIM * D_DIM) {
      int dcol = i2 >> 8, k = i2 & 255;
      wo_t[i2] = (bf16)wo[k * 256 + dcol];
    }
  }
}

// ---------------- K1: LayerNorm, one wave per row, write bf16 ----------------
__global__ __launch_bounds__(256) void ln_kernel(const float* __restrict__ x,
                                                 const float* __restrict__ sc,
                                                 const float* __restrict__ bs,
                                                 bf16* __restrict__ y) {
  int wid  = threadIdx.x >> 6;
  int lane = threadIdx.x & 63;
  int row  = blockIdx.x * 4 + wid;
  float4 v = ((const float4*)(x + (size_t)row * D_DIM))[lane];
  float s = v.x + v.y + v.z + v.w;
  #pragma unroll
  for (int m = 32; m; m >>= 1) s += __shfl_xor(s, m);
  float mu = s * (1.0f / 256.0f);
  float dx = v.x - mu, dy = v.y - mu, dz = v.z - mu, dw = v.w - mu;
  float s2 = dx * dx + dy * dy + dz * dz + dw * dw;
  #pragma unroll
  for (int m = 32; m; m >>= 1) s2 += __shfl_xor(s2, m);
  float rs = rsqrtf(s2 * (1.0f / 256.0f) + 1e-5f);
  float4 scv = ((const float4*)sc)[lane];
  float4 bsv = ((const float4*)bs)[lane];
  union { uint2 u; bf16 b[4]; } o;
  o.b[0] = (bf16)(dx * rs * scv.x + bsv.x);
  o.b[1] = (bf16)(dy * rs * scv.y + bsv.y);
  o.b[2] = (bf16)(dz * rs * scv.z + bsv.z);
  o.b[3] = (bf16)(dw * rs * scv.w + bsv.w);
  ((uint2*)y)[(size_t)row * 64 + lane] = o.u;
}

// swizzled LDS fragment read: logical (row, k-elem) in a [*][64] bf16 tile,
// physical byte = (row*128 + k*2) ^ ((row&7)<<4)
__device__ __forceinline__ bf16x8 lds_swz(const bf16* base, int row, int k) {
  return *(const bf16x8*)((const char*)base + ((((row << 6) + k) << 1) ^ ((row & 7) << 4)));
}

// ---------------- K2: QKVG GEMM -> attention-native panels ----------------
// A[65536][256] bf16 (rows s*512+res) @ WcatT[1024][256] ->
// pan[type][res][hpair][128 s][64 c] bf16 (type 0..3 = q,k,v,g; c = (h&1)*32 + cc).
// 128x128 tile (fixed s, 128 res), BK=64, gl16 pre-swizzled staging, sigmoid on g.
__global__ __launch_bounds__(256, 4) void gemm_qkvg(const bf16* __restrict__ A,
                                                    const bf16* __restrict__ Bt,
                                                    bf16* __restrict__ pan,
                                                    const float* __restrict__ bias) {
  __shared__ __align__(16) bf16 smem[16384];   // As|Bs; reused as C-stage
  bf16* As = smem;
  bf16* Bs = smem + 8192;
  const int tid  = threadIdx.x;
  const int wid  = tid >> 6;
  const int lane = tid & 63;
  const int bid   = blockIdx.x;
  const int n_idx = (bid >> 3) & 7;
  const int m_idx = (bid & 7) | ((bid >> 6) << 3);
  const int m0 = m_idx * 128;
  const int n0 = n_idx * 128;
  const int lrow = lane & 15;
  const int lk   = (lane >> 4) * 8;
  const int wr = wid >> 1, wc = wid & 1;

  const int ln8 = lane >> 3;
  const int c8  = ((lane & 7) ^ ln8) * 8;       // pre-swizzled source 16B slot

  const bf16* Arow = A  + (size_t)m0 * 256 + c8;
  const bf16* Brow = Bt + (size_t)n0 * 256 + c8;

  f32x4 acc[4][4] = {};

  #pragma unroll
  for (int ks = 0; ks < 4; ++ks) {
    const int k0 = ks * 64;
    #pragma unroll
    for (int t = 0; t < 4; ++t) {
      int chunk = wid * 4 + t;
      int r = chunk * 8 + ln8;
      gl16(&As[chunk * 512], Arow + (size_t)r * 256 + k0);
      gl16(&Bs[chunk * 512], Brow + (size_t)r * 256 + k0);
    }
    __syncthreads();
    #pragma unroll
    for (int kk = 0; kk < 64; kk += 32) {
      bf16x8 av[4], bv[4];
      #pragma unroll
      for (int i = 0; i < 4; ++i)
        av[i] = lds_swz(As, wr * 64 + i * 16 + lrow, kk + lk);
      #pragma unroll
      for (int j = 0; j < 4; ++j)
        bv[j] = lds_swz(Bs, wc * 64 + j * 16 + lrow, kk + lk);
      #pragma unroll
      for (int i = 0; i < 4; ++i)
        #pragma unroll
        for (int j = 0; j < 4; ++j)
          acc[i][j] = __builtin_amdgcn_mfma_f32_16x16x32_bf16(av[i], bv[j], acc[i][j], 0, 0, 0);
    }
    __syncthreads();
  }

  const int rb = (lane >> 4) * 4;
  const int xorv = rb << 2;

  const bool isg = (n_idx >= 6);                // type 3 = gate
  float bgv[4];
  if (isg) {
    #pragma unroll
    for (int j = 0; j < 4; ++j) bgv[j] = bias[(n_idx & 1) * 128 + wc * 64 + j * 16 + lrow];
  }
  #pragma unroll
  for (int i = 0; i < 4; ++i)
    #pragma unroll
    for (int j = 0; j < 4; ++j) {
      int col = wc * 64 + j * 16 + lrow;
      #pragma unroll
      for (int r = 0; r < 4; ++r) {
        int row = wr * 64 + i * 16 + rb + r;
        float v = acc[i][j][r];
        if (isg) { v += bgv[j]; v = 1.0f / (1.0f + __expf(-v)); }
        smem[row * 128 + (col ^ xorv)] = (bf16)v;
      }
    }
  __syncthreads();

  // panel store: tile = fixed s, res0..res0+127, type, hpairs hp0,hp0+1
  const int type = n_idx >> 1;
  const int hp0  = (n_idx & 1) * 2;
  const int s    = m_idx >> 2;
  const int res0 = (m_idx & 3) * 128;
  #pragma unroll
  for (int p = 0; p < 8; ++p) {
    int ch = p * 256 + tid;
    int c16 = ch & 7, hpl = (ch >> 3) & 1, rr = ch >> 4;
    int col = hpl * 64 + c16 * 8;
    *(uint4*)(pan + ((size_t)((type * 512 + res0 + rr) * 4) + hp0 + hpl) * 8192 + s * 64 + c16 * 8) =
        *(const uint4*)(smem + rr * 128 + (col ^ ((rr & 12) << 2)));
  }
}

// ---------------- K3: attention per (res, head-group of 4); wave = head -----------
// Zero barriers. All frag loads coalesced from panels. V^T staged wave-private.
// Gated o (bf16) -> obuf[(res*128+s)][256].
__global__ __launch_bounds__(256, 3) void attn_kernel(const bf16* __restrict__ pan,
                                                      bf16* __restrict__ obuf) {
  // vt 4x[32][136] (34816B) | pw 4x[16][72] (9216B) | os 4x[16][36] (4608B) = 48640B
  __shared__ __align__(16) char smem[48640];
  const int tid  = threadIdx.x;
  const int wid  = tid >> 6;
  const int lane = tid & 63;
  const int lrow = lane & 15;
  const int lkg  = lane >> 4;
  const int lk   = lkg * 8;
  const int rb   = lkg * 4;
  const int bid  = blockIdx.x;
  const int res  = bid >> 1;
  const int hg   = bid & 1;
  const int h    = hg * 4 + wid;
  const int hp   = h >> 1;
  const int hl   = (h & 1) * 32;

  bf16* vw  = (bf16*)smem + wid * (32 * 136);
  bf16* pwb = (bf16*)(smem + 34816) + wid * (16 * 72);
  bf16* osb = (bf16*)(smem + 44032) + wid * (16 * 36);

  const bf16* Pq = pan + ((size_t)((0 * 512 + res) * 4) + hp) * 8192 + hl;
  const bf16* Pk = pan + ((size_t)((1 * 512 + res) * 4) + hp) * 8192 + hl;
  const bf16* Pv = pan + ((size_t)((2 * 512 + res) * 4) + hp) * 8192 + hl;
  const bf16* Pg = pan + ((size_t)((3 * 512 + res) * 4) + hp) * 8192 + hl;

  // stage V^T (wave-private)
  {
    int t0 = lane >> 2, cs = (lane & 3) * 8;
    #pragma unroll
    for (int p = 0; p < 8; ++p) {
      int t = p * 16 + t0;
      union { uint4 u; bf16 e[8]; } v;
      v.u = *(const uint4*)(Pv + t * 64 + cs);
      #pragma unroll
      for (int j = 0; j < 8; ++j) vw[(cs + j) * 136 + t] = v.e[j];
    }
  }

  // K fragments in registers (coalesced panel reads)
  bf16x8 kf[8];
  #pragma unroll
  for (int tt = 0; tt < 8; ++tt)
    kf[tt] = *(const bf16x8*)(Pk + (tt * 16 + lrow) * 64 + lk);

  const float scale = 0.17677669529663687f; // 1/sqrt(32)
  const f32x4 z = {0.f, 0.f, 0.f, 0.f};

  for (int st = 0; st < 8; ++st) {
    bf16x8 qf = *(const bf16x8*)(Pq + (st * 16 + lrow) * 64 + lk);
    f32x4 sc[8];
    #pragma unroll
    for (int tt = 0; tt < 8; ++tt)
      sc[tt] = __builtin_amdgcn_mfma_f32_16x16x32_bf16(qf, kf[tt], z, 0, 0, 0);

    // softmax over t (in-lane 8 regs + 16-lane-group shuffles); q-row = rb+r
    #pragma unroll
    for (int r = 0; r < 4; ++r) {
      float m = sc[0][r];
      #pragma unroll
      for (int tc = 1; tc < 8; ++tc) m = fmaxf(m, sc[tc][r]);
      #pragma unroll
      for (int msk = 8; msk; msk >>= 1) m = fmaxf(m, __shfl_xor(m, msk));
      float pv[8], ssum = 0.f;
      #pragma unroll
      for (int tc = 0; tc < 8; ++tc) {
        float p = __expf((sc[tc][r] - m) * scale);
        pv[tc] = p; ssum += p;
      }
      #pragma unroll
      for (int msk = 8; msk; msk >>= 1) ssum += __shfl_xor(ssum, msk);
      float inv = 1.0f / ssum;
      #pragma unroll
      for (int tc = 0; tc < 8; ++tc) sc[tc][r] = pv[tc] * inv;
    }

    // PV through wave-private transpose buffer (two t-halves)
    f32x4 oc[2] = {z, z};
    #pragma unroll
    for (int hf = 0; hf < 2; ++hf) {
      #pragma unroll
      for (int tc = 0; tc < 4; ++tc)
        #pragma unroll
        for (int r = 0; r < 4; ++r)
          pwb[(rb + r) * 72 + tc * 16 + lrow] = (bf16)sc[hf * 4 + tc][r];
      #pragma unroll
      for (int kc = 0; kc < 2; ++kc) {
        bf16x8 pa = *(const bf16x8*)(pwb + lrow * 72 + kc * 32 + lk);
        #pragma unroll
        for (int ct = 0; ct < 2; ++ct) {
          bf16x8 bv = *(const bf16x8*)(vw + (ct * 16 + lrow) * 136 + hf * 64 + kc * 32 + lk);
          oc[ct] = __builtin_amdgcn_mfma_f32_16x16x32_bf16(pa, bv, oc[ct], 0, 0, 0);
        }
      }
    }
    // raw o strip -> os, then gated coalesced store
    #pragma unroll
    for (int ct = 0; ct < 2; ++ct)
      #pragma unroll
      for (int r = 0; r < 4; ++r)
        osb[(rb + r) * 36 + ct * 16 + lrow] = (bf16)oc[ct][r];
    {
      int row = lane >> 2, c16 = (lane & 3) * 8;
      bf16x8 o8 = *(const bf16x8*)(osb + row * 36 + c16);
      bf16x8 g8 = *(const bf16x8*)(Pg + (st * 16 + row) * 64 + c16);
      bf16x8 r8;
      #pragma unroll
      for (int u = 0; u < 8; ++u) r8[u] = (bf16)((float)o8[u] * (float)g8[u]);
      *(uint4*)(obuf + ((size_t)res * 128 + st * 16 + row) * 256 + h * 32 + c16) = *(uint4*)&r8;
    }
  }
}

// ---------------- K4: output projection: obuf[65536][256] @ woT + bo -> out -------
// rows of obuf are (res*128 + s); out row = s*512 + res (remapped at store).
__global__ __launch_bounds__(256, 4) void gemm_proj(const bf16* __restrict__ A,
                                                    const bf16* __restrict__ Bt,
                                                    float* __restrict__ Cout,
                                                    const float* __restrict__ bias) {
  __shared__ __align__(16) bf16 smem[16384];
  bf16* As = smem;
  bf16* Bs = smem + 8192;
  const int tid  = threadIdx.x;
  const int wid  = tid >> 6;
  const int lane = tid & 63;
  const int bid   = blockIdx.x;
  const int n_idx = (bid >> 3) & 1;
  const int m_idx = (bid & 7) | ((bid >> 4) << 3);
  const int m0 = m_idx * 128;
  const int n0 = n_idx * 128;
  const int lrow = lane & 15;
  const int lk   = (lane >> 4) * 8;
  const int wr = wid >> 1, wc = wid & 1;

  const int ln8 = lane >> 3;
  const int c8  = ((lane & 7) ^ ln8) * 8;

  const bf16* Arow = A  + (size_t)m0 * 256 + c8;
  const bf16* Brow = Bt + (size_t)n0 * 256 + c8;

  f32x4 acc[4][4] = {};

  #pragma unroll
  for (int ks = 0; ks < 4; ++ks) {
    const int k0 = ks * 64;
    #pragma unroll
    for (int t = 0; t < 4; ++t) {
      int chunk = wid * 4 + t;
      int r = chunk * 8 + ln8;
      gl16(&As[chunk * 512], Arow + (size_t)r * 256 + k0);
      gl16(&Bs[chunk * 512], Brow + (size_t)r * 256 + k0);
    }
    __syncthreads();
    #pragma unroll
    for (int kk = 0; kk < 64; kk += 32) {
      bf16x8 av[4], bv[4];
      #pragma unroll
      for (int i = 0; i < 4; ++i)
        av[i] = lds_swz(As, wr * 64 + i * 16 + lrow, kk + lk);
      #pragma unroll
      for (int j = 0; j < 4; ++j)
        bv[j] = lds_swz(Bs, wc * 64 + j * 16 + lrow, kk + lk);
      #pragma unroll
      for (int i = 0; i < 4; ++i)
        #pragma unroll
        for (int j = 0; j < 4; ++j)
          acc[i][j] = __builtin_amdgcn_mfma_f32_16x16x32_bf16(av[i], bv[j], acc[i][j], 0, 0, 0);
    }
    __syncthreads();
  }

  const int rb = (lane >> 4) * 4;
  const int xorv = rb << 2;
  float* smf = (float*)smem;
  float bov[4];
  #pragma unroll
  for (int j = 0; j < 4; ++j) bov[j] = bias[n0 + wc * 64 + j * 16 + lrow];
  #pragma unroll
  for (int half = 0; half < 2; ++half) {
    if (half) __syncthreads();
    #pragma unroll
    for (int i2 = 0; i2 < 2; ++i2) {
      int i = half * 2 + i2;
      #pragma unroll
      for (int j = 0; j < 4; ++j) {
        int col = wc * 64 + j * 16 + lrow;
        #pragma unroll
        for (int r = 0; r < 4; ++r) {
          int crow = wr * 32 + i2 * 16 + rb + r;
          smf[crow * 128 + (col ^ xorv)] = acc[i][j][r] + bov[j];
        }
      }
    }
    __syncthreads();
    #pragma unroll
    for (int p = 0; p < 8; ++p) {
      int ch = p * 256 + tid;
      int crow = ch >> 5, slot = (ch & 31) * 4;
      int rx = (crow & 12) << 2;
      int s_loc = (crow >> 5) * 64 + half * 32 + (crow & 31);
      *(uint4*)(Cout + ((size_t)s_loc * 512 + m_idx) * 256 + n0 + slot) =
          *(const uint4*)(smf + crow * 128 + (slot ^ rx));
    }
  }
}

// ---------------- launch ----------------
extern "C" void kernel_launch(void* const* d_in, const int* in_sizes, int n_in,
                              void* d_out, int out_size, void* d_ws, size_t ws_size,
                              hipStream_t stream) {
  const float* msa      = (const float*)d_in[0];
  const float* ln_scale = (const float*)d_in[1];
  const float* ln_bias  = (const float*)d_in[2];
  const float* wq       = (const float*)d_in[3];
  const float* wk       = (const float*)d_in[4];
  const float* wv       = (const float*)d_in[5];
  const float* wg       = (const float*)d_in[6];
  const float* bg       = (const float*)d_in[7];
  const float* wo       = (const float*)d_in[8];
  const float* bo       = (const float*)d_in[9];
  float* out = (float*)d_out;

  char* ws = (char*)d_ws;
  bf16* wcat_t = (bf16*)ws;                                  // 512 KB
  bf16* wo_t   = (bf16*)(ws + 524288);                       // 128 KB
  bf16* pan    = (bf16*)(ws + 655360);                       // 128 MB panels
  bf16* obuf   = (bf16*)(ws + 655360 + 134217728ULL);        // 32 MB gated o
  bf16* x_ln   = (bf16*)d_out;                               // 32 MB scratch (dead before gemm_proj writes)

  pack_weights<<<dim3(1280), dim3(256), 0, stream>>>(wq, wk, wv, wg, wo, wcat_t, wo_t);
  ln_kernel<<<dim3(65536 / 4), dim3(256), 0, stream>>>(msa, ln_scale, ln_bias, x_ln);
  gemm_qkvg<<<dim3(4096), dim3(256), 0, stream>>>(x_ln, wcat_t, pan, bg);
  attn_kernel<<<dim3(1024), dim3(256), 0, stream>>>(pan, obuf);
  gemm_proj<<<dim3(1024), dim3(256), 0, stream>>>(obuf, wo_t, out, bo);
}